// Round 10
// baseline (262.492 us; speedup 1.0000x reference)
//
#include <hip/hip_runtime.h>
#include <hip/hip_bf16.h>

// Round 10: R8 structure (proven) + (1) pos-L1 weights hoisted to registers
// (removes 64 loop-carried ds_read_b32/tile), (2) 2-dispatch scan, (3) num/den
// zeroing moved into fused_prep as a role; memset covers cursor only.

using bf16x8 = __attribute__((ext_vector_type(8))) short;
using f32x4  = __attribute__((ext_vector_type(4))) float;
using u16x8  = __attribute__((ext_vector_type(8))) unsigned short;
using u16x4  = __attribute__((ext_vector_type(4))) unsigned short;

__device__ __forceinline__ uint32_t cvtpk(float a, float b) {
  uint32_t d;
  asm("v_cvt_pk_bf16_f32 %0, %1, %2" : "=v"(d) : "v"(a), "v"(b));
  return d;
}
__device__ __forceinline__ float bf2f(unsigned short s) {
  union { uint32_t u; float f; } v; v.u = ((uint32_t)s) << 16;
  return v.f;
}
__device__ __forceinline__ float bf2fs(short s) { return bf2f((unsigned short)s); }
__device__ __forceinline__ bf16x8 mk8(uint32_t a, uint32_t b, uint32_t c, uint32_t d) {
  union { uint4 q; bf16x8 v; } u;
  u.q.x = a; u.q.y = b; u.q.z = c; u.q.w = d;
  return u.v;
}
__device__ __forceinline__ f32x4 mfma16(bf16x8 a, bf16x8 b, f32x4 c) {
  return __builtin_amdgcn_mfma_f32_16x16x32_bf16(a, b, c, 0, 0, 0);
}
#define LGKM0 asm volatile("s_waitcnt lgkmcnt(0)" ::: "memory")

// ================= fused prep: prepack + zero + hist + node_in =================
__global__ __launch_bounds__(256, 3) void fused_prep_kernel(
    const float* __restrict__ pW2, const float* __restrict__ aW1, const float* __restrict__ aW2,
    const float* __restrict__ W_in, const float* __restrict__ W_lin,
    const float* __restrict__ W_src, const float* __restrict__ W_dst,
    const float* __restrict__ W_out, uint4* __restrict__ frag,
    uint4* __restrict__ zbase, int zquads,
    const int* __restrict__ eidx, int* __restrict__ cursor, int E,
    const float* __restrict__ x, const float* __restrict__ b_in,
    unsigned short* __restrict__ vbf, unsigned short* __restrict__ abf,
    float* __restrict__ adst, int N, int ZB, int HB) {
  __shared__ uint32_t sWfrag[32][64][4];
  __shared__ float    sBias[64];
  __shared__ float    sXp[4][16 * 68];

  const int tid = threadIdx.x;

  // ---------- role: prepack (frag consumed ONLY by later dispatches) ----------
  if (blockIdx.x < 16) {
    const int idx = blockIdx.x * 256 + tid;
    const int f = idx >> 6, lane = idx & 63;
    const float* W; int fl;
    if      (f <  8) { W = pW2;   fl = f;      }
    else if (f < 16) { W = aW1;   fl = f -  8; }
    else if (f < 24) { W = aW2;   fl = f - 16; }
    else if (f < 32) { W = W_in;  fl = f - 24; }
    else if (f < 40) { W = W_lin; fl = f - 32; }
    else if (f < 48) { W = W_src; fl = f - 40; }
    else if (f < 56) { W = W_dst; fl = f - 48; }
    else             { W = W_out; fl = f - 56; }
    const int half = (fl >> 2) & 1, t = fl & 3;
    const int lo = lane & 15, hi = lane >> 4;
    const int c = t * 16 + lo;
    const int k = 32 * half + hi * 8;
    uint4 q;
    q.x = cvtpk(W[(k + 0) * 64 + c], W[(k + 1) * 64 + c]);
    q.y = cvtpk(W[(k + 2) * 64 + c], W[(k + 3) * 64 + c]);
    q.z = cvtpk(W[(k + 4) * 64 + c], W[(k + 5) * 64 + c]);
    q.w = cvtpk(W[(k + 6) * 64 + c], W[(k + 7) * 64 + c]);
    frag[idx] = q;
    return;
  }
  int bid = blockIdx.x - 16;

  // ---------- role: zero num/den (consumed by edge, 2 dispatches later) ----------
  if (bid < ZB) {
    const uint4 z = make_uint4(0, 0, 0, 0);
    for (int i = bid * 256 + tid; i < zquads; i += ZB * 256) zbase[i] = z;
    return;
  }
  bid -= ZB;

  // ---------- role: hist ----------
  if (bid < HB) {
    const int base = (bid * 256 + tid) * 4;
    if (base + 3 < E) {
      const int4 d = *(const int4*)(eidx + E + base);
      atomicAdd(&cursor[d.x], 1);
      atomicAdd(&cursor[d.y], 1);
      atomicAdd(&cursor[d.z], 1);
      atomicAdd(&cursor[d.w], 1);
    } else {
      for (int j = base; j < E; ++j) atomicAdd(&cursor[eidx[E + j]], 1);
    }
    return;
  }
  bid -= HB;
  const int nbn = gridDim.x - 16 - ZB - HB;

  // ---------- role: node_in (builds its OWN frags from raw weights) ----------
  for (int idx = tid; idx < 32 * 64; idx += 256) {
    const int f = idx >> 6, lane = idx & 63;
    const int m = f >> 3, half = (f >> 2) & 1, t = f & 3;
    const float* W = (m == 0) ? W_in : (m == 1) ? W_lin : (m == 2) ? W_src : W_dst;
    const int lo = lane & 15, hi = lane >> 4;
    const int c = t * 16 + lo;
    const int k = 32 * half + hi * 8;
    uint4 q;
    q.x = cvtpk(W[(k + 0) * 64 + c], W[(k + 1) * 64 + c]);
    q.y = cvtpk(W[(k + 2) * 64 + c], W[(k + 3) * 64 + c]);
    q.z = cvtpk(W[(k + 4) * 64 + c], W[(k + 5) * 64 + c]);
    q.w = cvtpk(W[(k + 6) * 64 + c], W[(k + 7) * 64 + c]);
    *(uint4*)&sWfrag[f][lane][0] = q;
  }
  if (tid < 64) sBias[tid] = b_in[tid];
  __syncthreads();

  const int w  = tid >> 6, l = tid & 63;
  const int lo = l & 15,  hi = l >> 4;
  float*   xb     = &sXp[w][0];
  uint8_t* trbase = (uint8_t*)xb;
  const uint32_t swz = (uint32_t)((lo & 7) << 4);
  const int rr = l >> 5, cc = l & 31;

#define WF(m, half, t) (*(const bf16x8*)&sWfrag[(m) * 8 + (half) * 4 + (t)][l][0])

  const int ntiles = (N + 15) >> 4;
  for (int tile = bid * 4 + w; tile < ntiles; tile += nbn * 4) {
    const int row = tile * 16 + lo;
    const int rowc = row < N ? row : (N - 1);
    bf16x8 xf[2];
#pragma unroll
    for (int half = 0; half < 2; ++half) {
      const int base = 32 * half + hi * 8;
      const f32x4 X0 = *(const f32x4*)&x[(size_t)rowc * 64 + base];
      const f32x4 X1 = *(const f32x4*)&x[(size_t)rowc * 64 + base + 4];
      xf[half] = mk8(cvtpk(X0[0], X0[1]), cvtpk(X0[2], X0[3]),
                     cvtpk(X1[0], X1[1]), cvtpk(X1[2], X1[3]));
    }
    f32x4 x1[4];
#pragma unroll
    for (int t = 0; t < 4; ++t) {
      f32x4 acc = *(const f32x4*)&sBias[t * 16 + hi * 4];
      acc = mfma16(WF(0, 0, t), xf[0], acc);
      acc = mfma16(WF(0, 1, t), xf[1], acc);
#pragma unroll
      for (int r = 0; r < 4; ++r) x1[t][r] = fmaxf(acc[r], 0.f);
    }
    LGKM0;
#pragma unroll
    for (int t = 0; t < 4; ++t) {
      uint2 p; p.x = cvtpk(x1[t][0], x1[t][1]); p.y = cvtpk(x1[t][2], x1[t][3]);
      *(uint2*)(trbase + lo * 128 + (((uint32_t)(t * 32 + hi * 8)) ^ swz)) = p;
    }
    LGKM0;
    const bf16x8 x1f0 = *(const bf16x8*)(trbase + lo * 128 + (((uint32_t)(hi * 16)) ^ swz));
    const bf16x8 x1f1 = *(const bf16x8*)(trbase + lo * 128 + (((uint32_t)(64 + hi * 16)) ^ swz));

#pragma unroll
    for (int m = 1; m <= 3; ++m) {
      f32x4 res[4];
#pragma unroll
      for (int t = 0; t < 4; ++t) {
        f32x4 acc = {0.f, 0.f, 0.f, 0.f};
        acc = mfma16(WF(m, 0, t), x1f0, acc);
        acc = mfma16(WF(m, 1, t), x1f1, acc);
        res[t] = acc;
      }
#pragma unroll
      for (int t = 0; t < 4; ++t)
        *(f32x4*)&xb[lo * 68 + t * 16 + hi * 4] = res[t];
      LGKM0;
      if (m == 3) {
#pragma unroll
        for (int ee = 0; ee < 16; ++ee) {
          const int r2 = tile * 16 + ee;
          if (r2 < N) adst[(size_t)r2 * 64 + l] = xb[ee * 68 + l];
        }
      } else {
        unsigned short* outp = (m == 1) ? vbf : abf;
#pragma unroll
        for (int ee2 = 0; ee2 < 16; ee2 += 2) {
          const int er = ee2 + rr;
          const int r2 = tile * 16 + er;
          const uint32_t pk = cvtpk(xb[er * 68 + 2 * cc], xb[er * 68 + 2 * cc + 1]);
          if (r2 < N) *(uint32_t*)&outp[(size_t)r2 * 64 + 2 * cc] = pk;
        }
      }
      LGKM0;
    }
  }
#undef WF
}

// ================= scan (2 dispatches) =================
#define SCAN_CH 1024
__global__ __launch_bounds__(256) void scan_blocksum(
    const int* __restrict__ cursor, int* __restrict__ bsum, int N) {
  __shared__ int red[4];
  const int base = blockIdx.x * SCAN_CH + threadIdx.x * 4;
  int s = 0;
#pragma unroll
  for (int j = 0; j < 4; ++j) { const int i = base + j; if (i < N) s += cursor[i]; }
  for (int off = 1; off < 64; off <<= 1) s += __shfl_xor(s, off);
  if ((threadIdx.x & 63) == 0) red[threadIdx.x >> 6] = s;
  __syncthreads();
  if (threadIdx.x == 0) bsum[blockIdx.x] = red[0] + red[1] + red[2] + red[3];
}

__global__ __launch_bounds__(256) void scan_final(
    int* __restrict__ cursor, const int* __restrict__ bsum, int N) {
  __shared__ int woff[4];
  __shared__ int sBoff;
  const int tid = threadIdx.x;
  const int base = blockIdx.x * SCAN_CH + tid * 4;
  int xv[4]; int s = 0;
#pragma unroll
  for (int j = 0; j < 4; ++j) { const int i = base + j; xv[j] = (i < N) ? cursor[i] : 0; s += xv[j]; }
  int v = s;
  const int lane = tid & 63, wid = tid >> 6;
  for (int off = 1; off < 64; off <<= 1) {
    const int u = __shfl_up(v, off);
    if (lane >= off) v += u;
  }
  if (lane == 63) woff[wid] = v;
  if (tid < 64) {   // wave 0 computes this block's bsum prefix (nb <= 64)
    int val = (tid < (int)blockIdx.x) ? bsum[tid] : 0;
    for (int off = 1; off < 64; off <<= 1) val += __shfl_xor(val, off);
    if (tid == 0) sBoff = val;
  }
  __syncthreads();
  int waveoff = 0;
#pragma unroll
  for (int k = 0; k < 4; ++k) waveoff += (k < wid) ? woff[k] : 0;
  int ex = sBoff + waveoff + (v - s);
#pragma unroll
  for (int j = 0; j < 4; ++j) {
    const int i = base + j;
    if (i < N) { cursor[i] = ex; ex += xv[j]; }
  }
}

__global__ __launch_bounds__(256) void scatter_kernel(
    const int* __restrict__ eidx, int* __restrict__ cursor,
    uint32_t* __restrict__ sorted, int E) {
  const int e = blockIdx.x * 256 + threadIdx.x;
  if (e < E) {
    const int s = eidx[e];
    const int d = eidx[E + e];
    const int slot = atomicAdd(&cursor[d], 1);
    sorted[slot] = ((uint32_t)d << 16) | (uint32_t)s;
  }
}

// ================= edge kernel (R8 + reg-hoisted pos-L1 weights) =================
__global__ __launch_bounds__(512, 4) void edge_mfma_kernel(
    const float* __restrict__ pos,
    const unsigned short* __restrict__ vbf, const unsigned short* __restrict__ abf,
    const float* __restrict__ adst,
    const float* __restrict__ pW1, const float* __restrict__ pb1,
    const float* __restrict__ pb2, const float* __restrict__ ab1, const float* __restrict__ ab2,
    const uint4* __restrict__ frag,
    const uint32_t* __restrict__ sorted,
    float* __restrict__ num, float* __restrict__ den, int E) {
  __shared__ uint32_t sWfrag[24][64][4];   // pW2(0-7), aW1(8-15), aW2(16-23)
  __shared__ float    sSmall[192];         // pb2(0-64), ab1(64-128), ab2(128-192)
  __shared__ float    sXp[8][16 * 68];
  __shared__ int      sDst[8][16];

  const int tid = threadIdx.x;
  if (tid < 192) {
    float val;
    if      (tid < 64)  val = pb2[tid];
    else if (tid < 128) val = ab1[tid - 64];
    else                val = ab2[tid - 128];
    sSmall[tid] = val;
  }
  {
    uint4* sW4 = (uint4*)sWfrag;
    for (int i = tid; i < 24 * 64; i += 512) sW4[i] = frag[i];
  }
  __syncthreads();

  const int w  = tid >> 6, l = tid & 63;
  const int lo = l & 15,  hi = l >> 4;
  float*   xb     = &sXp[w][0];
  uint8_t* trbase = (uint8_t*)xb;
  const uint32_t swz = (uint32_t)((lo & 7) << 4);
  const int ho = hi * 8;

  // hoist pos-L1 weight slices into registers (loop-invariant per lane)
  float pwa[16], pwb[16], pwc[16], pbb[16];
#pragma unroll
  for (int half = 0; half < 2; ++half)
#pragma unroll
    for (int i = 0; i < 8; ++i) {
      const int j = half * 8 + i;
      const int k = 32 * half + ho + i;
      pwa[j] = pW1[k];
      pwb[j] = pW1[64 + k];
      pwc[j] = pW1[128 + k];
      pbb[j] = pb1[k];
    }

#define WF(m, half, t) (*(const bf16x8*)&sWfrag[(m) * 8 + (half) * 4 + (t)][l][0])

  const int ntiles = (E + 15) >> 4;
  const int stride = gridDim.x * 8;

  int cs = 0, cd = 0; float c0 = 0.f, c1 = 0.f, c2 = 0.f;
  {
    const int t0 = blockIdx.x * 8 + w;
    if (t0 < ntiles) {
      const int ee = t0 * 16 + lo;
      const int ec = ee < E ? ee : (E - 1);
      const uint32_t se = sorted[ec];
      cs = (int)(se & 0xFFFFu); cd = (int)(se >> 16);
      c0 = pos[cd * 3 + 0] - pos[cs * 3 + 0];
      c1 = pos[cd * 3 + 1] - pos[cs * 3 + 1];
      c2 = pos[cd * 3 + 2] - pos[cs * 3 + 2];
    }
  }

  for (int tile = blockIdx.x * 8 + w; tile < ntiles; tile += stride) {
    const int src = cs, dst = cd;
    const float d0 = c0, d1 = c1, d2 = c2;
    const size_t db = (size_t)dst * 64, sb = (size_t)src * 64;

    const f32x4 Ad00 = *(const f32x4*)&adst[db + ho];
    const f32x4 Ad01 = *(const f32x4*)&adst[db + ho + 4];
    const f32x4 Ad10 = *(const f32x4*)&adst[db + 32 + ho];
    const f32x4 Ad11 = *(const f32x4*)&adst[db + 32 + ho + 4];
    const u16x8 As0  = *(const u16x8*)&abf[sb + ho];
    const u16x8 As1  = *(const u16x8*)&abf[sb + 32 + ho];

    const int nt = tile + stride;
    if (nt < ntiles) {
      const int ee = nt * 16 + lo;
      const int ec = ee < E ? ee : (E - 1);
      const uint32_t se = sorted[ec];
      cs = (int)(se & 0xFFFFu); cd = (int)(se >> 16);
      c0 = pos[cd * 3 + 0] - pos[cs * 3 + 0];
      c1 = pos[cd * 3 + 1] - pos[cs * 3 + 1];
      c2 = pos[cd * 3 + 2] - pos[cs * 3 + 2];
    }

    if (hi == 0) sDst[w][lo] = dst;

    // pos layer 1 (3->64) — all weights in registers, zero LDS reads
    bf16x8 hf[2];
#pragma unroll
    for (int half = 0; half < 2; ++half) {
      float t8[8];
#pragma unroll
      for (int i = 0; i < 8; ++i) {
        const int j = half * 8 + i;
        t8[i] = fmaxf(pbb[j] + d0 * pwa[j] + d1 * pwb[j] + d2 * pwc[j], 0.f);
      }
      hf[half] = mk8(cvtpk(t8[0], t8[1]), cvtpk(t8[2], t8[3]),
                     cvtpk(t8[4], t8[5]), cvtpk(t8[6], t8[7]));
    }
    // pos layer 2
    f32x4 dl[4];
#pragma unroll
    for (int t = 0; t < 4; ++t) {
      f32x4 acc = *(const f32x4*)&sSmall[t * 16 + hi * 4];
      acc = mfma16(WF(0, 0, t), hf[0], acc);
      acc = mfma16(WF(0, 1, t), hf[1], acc);
#pragma unroll
      for (int r = 0; r < 4; ++r) dl[t][r] = fmaxf(acc[r], 0.f);
    }
    // transpose delta
    LGKM0;
#pragma unroll
    for (int t = 0; t < 4; ++t) {
      uint2 p; p.x = cvtpk(dl[t][0], dl[t][1]); p.y = cvtpk(dl[t][2], dl[t][3]);
      *(uint2*)(trbase + lo * 128 + (((uint32_t)(t * 32 + hi * 8)) ^ swz)) = p;
    }
    LGKM0;
    const bf16x8 dfr0 = *(const bf16x8*)(trbase + lo * 128 + (((uint32_t)(hi * 16)) ^ swz));
    const bf16x8 dfr1 = *(const bf16x8*)(trbase + lo * 128 + (((uint32_t)(64 + hi * 16)) ^ swz));

    bf16x8 tf[2];
    {
      float t8[8];
#pragma unroll
      for (int i = 0; i < 8; ++i)
        t8[i] = ((i < 4) ? Ad00[i] : Ad01[i - 4]) - bf2f(As0[i]) + bf2fs(dfr0[i]);
      tf[0] = mk8(cvtpk(t8[0], t8[1]), cvtpk(t8[2], t8[3]),
                  cvtpk(t8[4], t8[5]), cvtpk(t8[6], t8[7]));
#pragma unroll
      for (int i = 0; i < 8; ++i)
        t8[i] = ((i < 4) ? Ad10[i] : Ad11[i - 4]) - bf2f(As1[i]) + bf2fs(dfr1[i]);
      tf[1] = mk8(cvtpk(t8[0], t8[1]), cvtpk(t8[2], t8[3]),
                  cvtpk(t8[4], t8[5]), cvtpk(t8[6], t8[7]));
    }

    u16x4 V[4];
#pragma unroll
    for (int t = 0; t < 4; ++t) V[t] = *(const u16x4*)&vbf[sb + t * 16 + hi * 4];

    // attn layer 1
    f32x4 ga[4];
#pragma unroll
    for (int t = 0; t < 4; ++t) {
      f32x4 acc = *(const f32x4*)&sSmall[64 + t * 16 + hi * 4];
      acc = mfma16(WF(1, 0, t), tf[0], acc);
      acc = mfma16(WF(1, 1, t), tf[1], acc);
#pragma unroll
      for (int r = 0; r < 4; ++r) ga[t][r] = fmaxf(acc[r], 0.f);
    }
#pragma unroll
    for (int t = 0; t < 4; ++t) {
      uint2 p; p.x = cvtpk(ga[t][0], ga[t][1]); p.y = cvtpk(ga[t][2], ga[t][3]);
      *(uint2*)(trbase + 2048 + lo * 128 + (((uint32_t)(t * 32 + hi * 8)) ^ swz)) = p;
    }
    LGKM0;
    const bf16x8 gf0 = *(const bf16x8*)(trbase + 2048 + lo * 128 + (((uint32_t)(hi * 16)) ^ swz));
    const bf16x8 gf1 = *(const bf16x8*)(trbase + 2048 + lo * 128 + (((uint32_t)(64 + hi * 16)) ^ swz));

    // attn layer 2 -> ex
    f32x4 exv[4];
#pragma unroll
    for (int t = 0; t < 4; ++t) {
      f32x4 acc = *(const f32x4*)&sSmall[128 + t * 16 + hi * 4];
      acc = mfma16(WF(2, 0, t), gf0, acc);
      acc = mfma16(WF(2, 1, t), gf1, acc);
      f32x4 nv;
#pragma unroll
      for (int r = 0; r < 4; ++r) {
        const float ex = __expf(fmaxf(acc[r], 0.f));
        exv[t][r] = ex;
        nv[r] = ex * (bf2f(V[t][r]) + dl[t][r]);
      }
      *(f32x4*)&xb[lo * 68 + t * 16 + hi * 4] = nv;
    }
    LGKM0;
    const int tbase = tile * 16;
    {
      int run_d = __builtin_amdgcn_readfirstlane(sDst[w][0]);
      float acc = 0.f;
#pragma unroll
      for (int ee = 0; ee < 16; ++ee) {
        if (tbase + ee < E) {
          const int de = __builtin_amdgcn_readfirstlane(sDst[w][ee]);
          const float nv = xb[ee * 68 + l];
          if (de != run_d) {
            atomicAdd(&num[(size_t)run_d * 64 + l], acc);
            run_d = de; acc = 0.f;
          }
          acc += nv;
        }
      }
      atomicAdd(&num[(size_t)run_d * 64 + l], acc);
    }
#pragma unroll
    for (int t = 0; t < 4; ++t)
      *(f32x4*)&xb[lo * 68 + t * 16 + hi * 4] = exv[t];
    LGKM0;
    {
      int run_d = __builtin_amdgcn_readfirstlane(sDst[w][0]);
      float acc = 0.f;
#pragma unroll
      for (int ee = 0; ee < 16; ++ee) {
        if (tbase + ee < E) {
          const int de = __builtin_amdgcn_readfirstlane(sDst[w][ee]);
          const float dv = xb[ee * 68 + l];
          if (de != run_d) {
            atomicAdd(&den[(size_t)run_d * 64 + l], acc);
            run_d = de; acc = 0.f;
          }
          acc += dv;
        }
      }
      atomicAdd(&den[(size_t)run_d * 64 + l], acc);
    }
  }
#undef WF
}

// ================= node_out (MFMA) =================
__global__ __launch_bounds__(512, 4) void node_out_mfma(
    const float* __restrict__ num, const float* __restrict__ den,
    const uint4* __restrict__ frag, const float* __restrict__ b_out,
    float* __restrict__ out, int N) {
  __shared__ uint32_t sWfrag[8][64][4];
  __shared__ float    sBias[64];
  __shared__ float    sXp[8][16 * 68];

  const int tid = threadIdx.x;
  {
    uint4* sW4 = (uint4*)sWfrag;
    const uint4* srcf = frag + 56 * 64;
    for (int i = tid; i < 8 * 64; i += 512) sW4[i] = srcf[i];
  }
  if (tid < 64) sBias[tid] = b_out[tid];
  __syncthreads();

  const int w  = tid >> 6, l = tid & 63;
  const int lo = l & 15,  hi = l >> 4;
  float* xb = &sXp[w][0];

#define WFo(half, t) (*(const bf16x8*)&sWfrag[(half) * 4 + (t)][l][0])

  const int ntiles = (N + 15) >> 4;
  for (int tile = blockIdx.x * 8 + w; tile < ntiles; tile += gridDim.x * 8) {
    const int row = tile * 16 + lo;
    const int rowc = row < N ? row : (N - 1);
    bf16x8 sf[2];
#pragma unroll
    for (int half = 0; half < 2; ++half) {
      const int base = 32 * half + hi * 8;
      const f32x4 N0 = *(const f32x4*)&num[(size_t)rowc * 64 + base];
      const f32x4 N1 = *(const f32x4*)&num[(size_t)rowc * 64 + base + 4];
      const f32x4 D0 = *(const f32x4*)&den[(size_t)rowc * 64 + base];
      const f32x4 D1 = *(const f32x4*)&den[(size_t)rowc * 64 + base + 4];
      float t8[8];
#pragma unroll
      for (int i = 0; i < 8; ++i) {
        const float nn = (i < 4) ? N0[i] : N1[i - 4];
        const float dd = (i < 4) ? D0[i] : D1[i - 4];
        t8[i] = nn / (dd + 1e-16f);
      }
      sf[half] = mk8(cvtpk(t8[0], t8[1]), cvtpk(t8[2], t8[3]),
                     cvtpk(t8[4], t8[5]), cvtpk(t8[6], t8[7]));
    }
    f32x4 res[4];
#pragma unroll
    for (int t = 0; t < 4; ++t) {
      f32x4 acc = *(const f32x4*)&sBias[t * 16 + hi * 4];
      acc = mfma16(WFo(0, t), sf[0], acc);
      acc = mfma16(WFo(1, t), sf[1], acc);
#pragma unroll
      for (int r = 0; r < 4; ++r) res[t][r] = fmaxf(acc[r], 0.f);
    }
    LGKM0;
#pragma unroll
    for (int t = 0; t < 4; ++t)
      *(f32x4*)&xb[lo * 68 + t * 16 + hi * 4] = res[t];
    LGKM0;
#pragma unroll
    for (int ee = 0; ee < 16; ++ee) {
      const int r2 = tile * 16 + ee;
      if (r2 < N) out[(size_t)r2 * 64 + l] = xb[ee * 68 + l];
    }
  }
#undef WFo
}

extern "C" void kernel_launch(void* const* d_in, const int* in_sizes, int n_in,
                              void* d_out, int out_size, void* d_ws, size_t ws_size,
                              hipStream_t stream) {
  const float* x     = (const float*)d_in[0];
  const float* pos   = (const float*)d_in[1];
  const float* W_in  = (const float*)d_in[2];
  const float* b_in  = (const float*)d_in[3];
  const float* W_lin = (const float*)d_in[4];
  const float* W_src = (const float*)d_in[5];
  const float* W_dst = (const float*)d_in[6];
  const float* pW1   = (const float*)d_in[7];
  const float* pb1   = (const float*)d_in[8];
  const float* pW2   = (const float*)d_in[9];
  const float* pb2   = (const float*)d_in[10];
  const float* aW1   = (const float*)d_in[11];
  const float* ab1   = (const float*)d_in[12];
  const float* aW2   = (const float*)d_in[13];
  const float* ab2   = (const float*)d_in[14];
  const float* W_out = (const float*)d_in[15];
  const float* b_out = (const float*)d_in[16];
  const int*   eidx  = (const int*)d_in[17];

  const int N = in_sizes[0] / 64;
  const int E = in_sizes[17] / 2;

  // workspace layout: cursor first (only memset region)
  char* p = (char*)d_ws;
  int*   cursor = (int*)p;    p += (size_t)N * 4;
  const size_t memset_bytes = (size_t)p - (size_t)d_ws;
  int*   bsum   = (int*)p;    p += 64 * 4;
  p = (char*)(((uintptr_t)p + 15) & ~(uintptr_t)15);
  float* num    = (float*)p;  p += (size_t)N * 64 * 4;
  float* den    = (float*)p;  p += (size_t)N * 64 * 4;
  uint4* frag   = (uint4*)p;  p += (size_t)4096 * 16;
  uint32_t* sorted = (uint32_t*)p; p += (size_t)E * 4;
  unsigned short* vbf = (unsigned short*)p; p += (size_t)N * 64 * 2;
  unsigned short* abf = (unsigned short*)p; p += (size_t)N * 64 * 2;
  float* adst   = (float*)p;  p += (size_t)N * 64 * 4;

  hipMemsetAsync(cursor, 0, memset_bytes, stream);

  const int ZB = 104;                    // zero-role blocks (num+den = 2*N*64 f32)
  const int zquads = 2 * N * 16;         // 16B quads
  const int HB = (E + 1023) / 1024;      // hist blocks (4 edges/thread)
  const int NB_NODE = 784;
  fused_prep_kernel<<<16 + ZB + HB + NB_NODE, 256, 0, stream>>>(
      pW2, aW1, aW2, W_in, W_lin, W_src, W_dst, W_out, frag,
      (uint4*)num, zquads,
      eidx, cursor, E,
      x, b_in, vbf, abf, adst, N, ZB, HB);

  const int nb = (N + SCAN_CH - 1) / SCAN_CH;
  scan_blocksum<<<nb, 256, 0, stream>>>(cursor, bsum, N);
  scan_final<<<nb, 256, 0, stream>>>(cursor, bsum, N);
  scatter_kernel<<<(E + 255) / 256, 256, 0, stream>>>(eidx, cursor, sorted, E);

  edge_mfma_kernel<<<512, 512, 0, stream>>>(pos, vbf, abf, adst,
                                            pW1, pb1, pb2, ab1, ab2,
                                            frag, sorted, num, den, E);
  node_out_mfma<<<392, 512, 0, stream>>>(num, den, frag, b_out, (float*)d_out, N);
}

// Round 11
// 208.210 us; speedup vs baseline: 1.2607x; 1.2607x over previous
//
#include <hip/hip_runtime.h>
#include <hip/hip_bf16.h>

// Round 11: edge kernel reverted EXACTLY to R8 (proven 96us; R9/R10 hoists
// spilled to scratch -> +225MB FETCH). Aux keeps R10 structure: fused_prep
// {prepack + zero(num/den) + hist + node_in}, 2-dispatch scan, cursor-only memset.

using bf16x8 = __attribute__((ext_vector_type(8))) short;
using f32x4  = __attribute__((ext_vector_type(4))) float;
using u16x8  = __attribute__((ext_vector_type(8))) unsigned short;
using u16x4  = __attribute__((ext_vector_type(4))) unsigned short;

__device__ __forceinline__ uint32_t cvtpk(float a, float b) {
  uint32_t d;
  asm("v_cvt_pk_bf16_f32 %0, %1, %2" : "=v"(d) : "v"(a), "v"(b));
  return d;
}
__device__ __forceinline__ float bf2f(unsigned short s) {
  union { uint32_t u; float f; } v; v.u = ((uint32_t)s) << 16;
  return v.f;
}
__device__ __forceinline__ float bf2fs(short s) { return bf2f((unsigned short)s); }
__device__ __forceinline__ bf16x8 mk8(uint32_t a, uint32_t b, uint32_t c, uint32_t d) {
  union { uint4 q; bf16x8 v; } u;
  u.q.x = a; u.q.y = b; u.q.z = c; u.q.w = d;
  return u.v;
}
__device__ __forceinline__ f32x4 mfma16(bf16x8 a, bf16x8 b, f32x4 c) {
  return __builtin_amdgcn_mfma_f32_16x16x32_bf16(a, b, c, 0, 0, 0);
}
#define LGKM0 asm volatile("s_waitcnt lgkmcnt(0)" ::: "memory")

// ================= fused prep: prepack + zero + hist + node_in =================
__global__ __launch_bounds__(256, 3) void fused_prep_kernel(
    const float* __restrict__ pW2, const float* __restrict__ aW1, const float* __restrict__ aW2,
    const float* __restrict__ W_in, const float* __restrict__ W_lin,
    const float* __restrict__ W_src, const float* __restrict__ W_dst,
    const float* __restrict__ W_out, uint4* __restrict__ frag,
    uint4* __restrict__ zbase, int zquads,
    const int* __restrict__ eidx, int* __restrict__ cursor, int E,
    const float* __restrict__ x, const float* __restrict__ b_in,
    unsigned short* __restrict__ vbf, unsigned short* __restrict__ abf,
    float* __restrict__ adst, int N, int ZB, int HB) {
  __shared__ uint32_t sWfrag[32][64][4];
  __shared__ float    sBias[64];
  __shared__ float    sXp[4][16 * 68];

  const int tid = threadIdx.x;

  // ---------- role: prepack (frag consumed ONLY by later dispatches) ----------
  if (blockIdx.x < 16) {
    const int idx = blockIdx.x * 256 + tid;
    const int f = idx >> 6, lane = idx & 63;
    const float* W; int fl;
    if      (f <  8) { W = pW2;   fl = f;      }
    else if (f < 16) { W = aW1;   fl = f -  8; }
    else if (f < 24) { W = aW2;   fl = f - 16; }
    else if (f < 32) { W = W_in;  fl = f - 24; }
    else if (f < 40) { W = W_lin; fl = f - 32; }
    else if (f < 48) { W = W_src; fl = f - 40; }
    else if (f < 56) { W = W_dst; fl = f - 48; }
    else             { W = W_out; fl = f - 56; }
    const int half = (fl >> 2) & 1, t = fl & 3;
    const int lo = lane & 15, hi = lane >> 4;
    const int c = t * 16 + lo;
    const int k = 32 * half + hi * 8;
    uint4 q;
    q.x = cvtpk(W[(k + 0) * 64 + c], W[(k + 1) * 64 + c]);
    q.y = cvtpk(W[(k + 2) * 64 + c], W[(k + 3) * 64 + c]);
    q.z = cvtpk(W[(k + 4) * 64 + c], W[(k + 5) * 64 + c]);
    q.w = cvtpk(W[(k + 6) * 64 + c], W[(k + 7) * 64 + c]);
    frag[idx] = q;
    return;
  }
  int bid = blockIdx.x - 16;

  // ---------- role: zero num/den (consumed by edge, 2+ dispatches later) ----------
  if (bid < ZB) {
    const uint4 z = make_uint4(0, 0, 0, 0);
    for (int i = bid * 256 + tid; i < zquads; i += ZB * 256) zbase[i] = z;
    return;
  }
  bid -= ZB;

  // ---------- role: hist ----------
  if (bid < HB) {
    const int base = (bid * 256 + tid) * 4;
    if (base + 3 < E) {
      const int4 d = *(const int4*)(eidx + E + base);
      atomicAdd(&cursor[d.x], 1);
      atomicAdd(&cursor[d.y], 1);
      atomicAdd(&cursor[d.z], 1);
      atomicAdd(&cursor[d.w], 1);
    } else {
      for (int j = base; j < E; ++j) atomicAdd(&cursor[eidx[E + j]], 1);
    }
    return;
  }
  bid -= HB;
  const int nbn = gridDim.x - 16 - ZB - HB;

  // ---------- role: node_in (builds its OWN frags from raw weights) ----------
  for (int idx = tid; idx < 32 * 64; idx += 256) {
    const int f = idx >> 6, lane = idx & 63;
    const int m = f >> 3, half = (f >> 2) & 1, t = f & 3;
    const float* W = (m == 0) ? W_in : (m == 1) ? W_lin : (m == 2) ? W_src : W_dst;
    const int lo = lane & 15, hi = lane >> 4;
    const int c = t * 16 + lo;
    const int k = 32 * half + hi * 8;
    uint4 q;
    q.x = cvtpk(W[(k + 0) * 64 + c], W[(k + 1) * 64 + c]);
    q.y = cvtpk(W[(k + 2) * 64 + c], W[(k + 3) * 64 + c]);
    q.z = cvtpk(W[(k + 4) * 64 + c], W[(k + 5) * 64 + c]);
    q.w = cvtpk(W[(k + 6) * 64 + c], W[(k + 7) * 64 + c]);
    *(uint4*)&sWfrag[f][lane][0] = q;
  }
  if (tid < 64) sBias[tid] = b_in[tid];
  __syncthreads();

  const int w  = tid >> 6, l = tid & 63;
  const int lo = l & 15,  hi = l >> 4;
  float*   xb     = &sXp[w][0];
  uint8_t* trbase = (uint8_t*)xb;
  const uint32_t swz = (uint32_t)((lo & 7) << 4);
  const int rr = l >> 5, cc = l & 31;

#define WF(m, half, t) (*(const bf16x8*)&sWfrag[(m) * 8 + (half) * 4 + (t)][l][0])

  const int ntiles = (N + 15) >> 4;
  for (int tile = bid * 4 + w; tile < ntiles; tile += nbn * 4) {
    const int row = tile * 16 + lo;
    const int rowc = row < N ? row : (N - 1);
    bf16x8 xf[2];
#pragma unroll
    for (int half = 0; half < 2; ++half) {
      const int base = 32 * half + hi * 8;
      const f32x4 X0 = *(const f32x4*)&x[(size_t)rowc * 64 + base];
      const f32x4 X1 = *(const f32x4*)&x[(size_t)rowc * 64 + base + 4];
      xf[half] = mk8(cvtpk(X0[0], X0[1]), cvtpk(X0[2], X0[3]),
                     cvtpk(X1[0], X1[1]), cvtpk(X1[2], X1[3]));
    }
    f32x4 x1[4];
#pragma unroll
    for (int t = 0; t < 4; ++t) {
      f32x4 acc = *(const f32x4*)&sBias[t * 16 + hi * 4];
      acc = mfma16(WF(0, 0, t), xf[0], acc);
      acc = mfma16(WF(0, 1, t), xf[1], acc);
#pragma unroll
      for (int r = 0; r < 4; ++r) x1[t][r] = fmaxf(acc[r], 0.f);
    }
    LGKM0;
#pragma unroll
    for (int t = 0; t < 4; ++t) {
      uint2 p; p.x = cvtpk(x1[t][0], x1[t][1]); p.y = cvtpk(x1[t][2], x1[t][3]);
      *(uint2*)(trbase + lo * 128 + (((uint32_t)(t * 32 + hi * 8)) ^ swz)) = p;
    }
    LGKM0;
    const bf16x8 x1f0 = *(const bf16x8*)(trbase + lo * 128 + (((uint32_t)(hi * 16)) ^ swz));
    const bf16x8 x1f1 = *(const bf16x8*)(trbase + lo * 128 + (((uint32_t)(64 + hi * 16)) ^ swz));

#pragma unroll
    for (int m = 1; m <= 3; ++m) {
      f32x4 res[4];
#pragma unroll
      for (int t = 0; t < 4; ++t) {
        f32x4 acc = {0.f, 0.f, 0.f, 0.f};
        acc = mfma16(WF(m, 0, t), x1f0, acc);
        acc = mfma16(WF(m, 1, t), x1f1, acc);
        res[t] = acc;
      }
#pragma unroll
      for (int t = 0; t < 4; ++t)
        *(f32x4*)&xb[lo * 68 + t * 16 + hi * 4] = res[t];
      LGKM0;
      if (m == 3) {
#pragma unroll
        for (int ee = 0; ee < 16; ++ee) {
          const int r2 = tile * 16 + ee;
          if (r2 < N) adst[(size_t)r2 * 64 + l] = xb[ee * 68 + l];
        }
      } else {
        unsigned short* outp = (m == 1) ? vbf : abf;
#pragma unroll
        for (int ee2 = 0; ee2 < 16; ee2 += 2) {
          const int er = ee2 + rr;
          const int r2 = tile * 16 + er;
          const uint32_t pk = cvtpk(xb[er * 68 + 2 * cc], xb[er * 68 + 2 * cc + 1]);
          if (r2 < N) *(uint32_t*)&outp[(size_t)r2 * 64 + 2 * cc] = pk;
        }
      }
      LGKM0;
    }
  }
#undef WF
}

// ================= scan (2 dispatches) =================
#define SCAN_CH 1024
__global__ __launch_bounds__(256) void scan_blocksum(
    const int* __restrict__ cursor, int* __restrict__ bsum, int N) {
  __shared__ int red[4];
  const int base = blockIdx.x * SCAN_CH + threadIdx.x * 4;
  int s = 0;
#pragma unroll
  for (int j = 0; j < 4; ++j) { const int i = base + j; if (i < N) s += cursor[i]; }
  for (int off = 1; off < 64; off <<= 1) s += __shfl_xor(s, off);
  if ((threadIdx.x & 63) == 0) red[threadIdx.x >> 6] = s;
  __syncthreads();
  if (threadIdx.x == 0) bsum[blockIdx.x] = red[0] + red[1] + red[2] + red[3];
}

__global__ __launch_bounds__(256) void scan_final(
    int* __restrict__ cursor, const int* __restrict__ bsum, int N) {
  __shared__ int woff[4];
  __shared__ int sBoff;
  const int tid = threadIdx.x;
  const int base = blockIdx.x * SCAN_CH + tid * 4;
  int xv[4]; int s = 0;
#pragma unroll
  for (int j = 0; j < 4; ++j) { const int i = base + j; xv[j] = (i < N) ? cursor[i] : 0; s += xv[j]; }
  int v = s;
  const int lane = tid & 63, wid = tid >> 6;
  for (int off = 1; off < 64; off <<= 1) {
    const int u = __shfl_up(v, off);
    if (lane >= off) v += u;
  }
  if (lane == 63) woff[wid] = v;
  if (tid < 64) {   // wave 0 computes this block's bsum prefix (nb <= 64)
    int val = (tid < (int)blockIdx.x) ? bsum[tid] : 0;
    for (int off = 1; off < 64; off <<= 1) val += __shfl_xor(val, off);
    if (tid == 0) sBoff = val;
  }
  __syncthreads();
  int waveoff = 0;
#pragma unroll
  for (int k = 0; k < 4; ++k) waveoff += (k < wid) ? woff[k] : 0;
  int ex = sBoff + waveoff + (v - s);
#pragma unroll
  for (int j = 0; j < 4; ++j) {
    const int i = base + j;
    if (i < N) { cursor[i] = ex; ex += xv[j]; }
  }
}

__global__ __launch_bounds__(256) void scatter_kernel(
    const int* __restrict__ eidx, int* __restrict__ cursor,
    uint32_t* __restrict__ sorted, int E) {
  const int e = blockIdx.x * 256 + threadIdx.x;
  if (e < E) {
    const int s = eidx[e];
    const int d = eidx[E + e];
    const int slot = atomicAdd(&cursor[d], 1);
    sorted[slot] = ((uint32_t)d << 16) | (uint32_t)s;
  }
}

// ================= edge kernel (EXACT R8 version) =================
__global__ __launch_bounds__(512, 4) void edge_mfma_kernel(
    const float* __restrict__ pos,
    const unsigned short* __restrict__ vbf, const unsigned short* __restrict__ abf,
    const float* __restrict__ adst,
    const float* __restrict__ pW1, const float* __restrict__ pb1,
    const float* __restrict__ pb2, const float* __restrict__ ab1, const float* __restrict__ ab2,
    const uint4* __restrict__ frag,
    const uint32_t* __restrict__ sorted,
    float* __restrict__ num, float* __restrict__ den, int E) {
  __shared__ uint32_t sWfrag[24][64][4];
  __shared__ float    sSmall[448];
  __shared__ float    sXp[8][16 * 68];
  __shared__ int      sDst[8][16];

  const int tid = threadIdx.x;
  for (int i = tid; i < 448; i += 512) {
    float val;
    if      (i < 192) val = pW1[i];
    else if (i < 256) val = pb1[i - 192];
    else if (i < 320) val = pb2[i - 256];
    else if (i < 384) val = ab1[i - 320];
    else              val = ab2[i - 384];
    sSmall[i] = val;
  }
  {
    uint4* sW4 = (uint4*)sWfrag;
    for (int i = tid; i < 24 * 64; i += 512) sW4[i] = frag[i];
  }
  __syncthreads();

  const int w  = tid >> 6, l = tid & 63;
  const int lo = l & 15,  hi = l >> 4;
  float*   xb     = &sXp[w][0];
  uint8_t* trbase = (uint8_t*)xb;
  const uint32_t swz = (uint32_t)((lo & 7) << 4);
  const int ho = hi * 8;

#define WF(m, half, t) (*(const bf16x8*)&sWfrag[(m) * 8 + (half) * 4 + (t)][l][0])

  const int ntiles = (E + 15) >> 4;
  const int stride = gridDim.x * 8;

  int cs = 0, cd = 0; float c0 = 0.f, c1 = 0.f, c2 = 0.f;
  {
    const int t0 = blockIdx.x * 8 + w;
    if (t0 < ntiles) {
      const int ee = t0 * 16 + lo;
      const int ec = ee < E ? ee : (E - 1);
      const uint32_t se = sorted[ec];
      cs = (int)(se & 0xFFFFu); cd = (int)(se >> 16);
      c0 = pos[cd * 3 + 0] - pos[cs * 3 + 0];
      c1 = pos[cd * 3 + 1] - pos[cs * 3 + 1];
      c2 = pos[cd * 3 + 2] - pos[cs * 3 + 2];
    }
  }

  for (int tile = blockIdx.x * 8 + w; tile < ntiles; tile += stride) {
    const int src = cs, dst = cd;
    const float d0 = c0, d1 = c1, d2 = c2;
    const size_t db = (size_t)dst * 64, sb = (size_t)src * 64;

    const f32x4 Ad00 = *(const f32x4*)&adst[db + ho];
    const f32x4 Ad01 = *(const f32x4*)&adst[db + ho + 4];
    const f32x4 Ad10 = *(const f32x4*)&adst[db + 32 + ho];
    const f32x4 Ad11 = *(const f32x4*)&adst[db + 32 + ho + 4];
    const u16x8 As0  = *(const u16x8*)&abf[sb + ho];
    const u16x8 As1  = *(const u16x8*)&abf[sb + 32 + ho];

    const int nt = tile + stride;
    if (nt < ntiles) {
      const int ee = nt * 16 + lo;
      const int ec = ee < E ? ee : (E - 1);
      const uint32_t se = sorted[ec];
      cs = (int)(se & 0xFFFFu); cd = (int)(se >> 16);
      c0 = pos[cd * 3 + 0] - pos[cs * 3 + 0];
      c1 = pos[cd * 3 + 1] - pos[cs * 3 + 1];
      c2 = pos[cd * 3 + 2] - pos[cs * 3 + 2];
    }

    if (hi == 0) sDst[w][lo] = dst;

    // pos layer 1 (3->64)
    bf16x8 hf[2];
#pragma unroll
    for (int half = 0; half < 2; ++half) {
      float t8[8];
#pragma unroll
      for (int i = 0; i < 8; ++i) {
        const int k = 32 * half + hi * 8 + i;
        t8[i] = fmaxf(sSmall[192 + k] + d0 * sSmall[k] + d1 * sSmall[64 + k] + d2 * sSmall[128 + k], 0.f);
      }
      hf[half] = mk8(cvtpk(t8[0], t8[1]), cvtpk(t8[2], t8[3]),
                     cvtpk(t8[4], t8[5]), cvtpk(t8[6], t8[7]));
    }
    // pos layer 2
    f32x4 dl[4];
#pragma unroll
    for (int t = 0; t < 4; ++t) {
      f32x4 acc = *(const f32x4*)&sSmall[256 + t * 16 + hi * 4];
      acc = mfma16(WF(0, 0, t), hf[0], acc);
      acc = mfma16(WF(0, 1, t), hf[1], acc);
#pragma unroll
      for (int r = 0; r < 4; ++r) dl[t][r] = fmaxf(acc[r], 0.f);
    }
    // transpose delta
    LGKM0;
#pragma unroll
    for (int t = 0; t < 4; ++t) {
      uint2 p; p.x = cvtpk(dl[t][0], dl[t][1]); p.y = cvtpk(dl[t][2], dl[t][3]);
      *(uint2*)(trbase + lo * 128 + (((uint32_t)(t * 32 + hi * 8)) ^ swz)) = p;
    }
    LGKM0;
    const bf16x8 dfr0 = *(const bf16x8*)(trbase + lo * 128 + (((uint32_t)(hi * 16)) ^ swz));
    const bf16x8 dfr1 = *(const bf16x8*)(trbase + lo * 128 + (((uint32_t)(64 + hi * 16)) ^ swz));

    bf16x8 tf[2];
    {
      float t8[8];
#pragma unroll
      for (int i = 0; i < 8; ++i)
        t8[i] = ((i < 4) ? Ad00[i] : Ad01[i - 4]) - bf2f(As0[i]) + bf2fs(dfr0[i]);
      tf[0] = mk8(cvtpk(t8[0], t8[1]), cvtpk(t8[2], t8[3]),
                  cvtpk(t8[4], t8[5]), cvtpk(t8[6], t8[7]));
#pragma unroll
      for (int i = 0; i < 8; ++i)
        t8[i] = ((i < 4) ? Ad10[i] : Ad11[i - 4]) - bf2f(As1[i]) + bf2fs(dfr1[i]);
      tf[1] = mk8(cvtpk(t8[0], t8[1]), cvtpk(t8[2], t8[3]),
                  cvtpk(t8[4], t8[5]), cvtpk(t8[6], t8[7]));
    }

    u16x4 V[4];
#pragma unroll
    for (int t = 0; t < 4; ++t) V[t] = *(const u16x4*)&vbf[sb + t * 16 + hi * 4];

    // attn layer 1
    f32x4 ga[4];
#pragma unroll
    for (int t = 0; t < 4; ++t) {
      f32x4 acc = *(const f32x4*)&sSmall[320 + t * 16 + hi * 4];
      acc = mfma16(WF(1, 0, t), tf[0], acc);
      acc = mfma16(WF(1, 1, t), tf[1], acc);
#pragma unroll
      for (int r = 0; r < 4; ++r) ga[t][r] = fmaxf(acc[r], 0.f);
    }
#pragma unroll
    for (int t = 0; t < 4; ++t) {
      uint2 p; p.x = cvtpk(ga[t][0], ga[t][1]); p.y = cvtpk(ga[t][2], ga[t][3]);
      *(uint2*)(trbase + 2048 + lo * 128 + (((uint32_t)(t * 32 + hi * 8)) ^ swz)) = p;
    }
    LGKM0;
    const bf16x8 gf0 = *(const bf16x8*)(trbase + 2048 + lo * 128 + (((uint32_t)(hi * 16)) ^ swz));
    const bf16x8 gf1 = *(const bf16x8*)(trbase + 2048 + lo * 128 + (((uint32_t)(64 + hi * 16)) ^ swz));

    // attn layer 2 -> ex
    f32x4 exv[4];
#pragma unroll
    for (int t = 0; t < 4; ++t) {
      f32x4 acc = *(const f32x4*)&sSmall[384 + t * 16 + hi * 4];
      acc = mfma16(WF(2, 0, t), gf0, acc);
      acc = mfma16(WF(2, 1, t), gf1, acc);
      f32x4 nv;
#pragma unroll
      for (int r = 0; r < 4; ++r) {
        const float ex = __expf(fmaxf(acc[r], 0.f));
        exv[t][r] = ex;
        nv[r] = ex * (bf2f(V[t][r]) + dl[t][r]);
      }
      *(f32x4*)&xb[lo * 68 + t * 16 + hi * 4] = nv;
    }
    LGKM0;
    const int tbase = tile * 16;
    {
      int run_d = __builtin_amdgcn_readfirstlane(sDst[w][0]);
      float acc = 0.f;
#pragma unroll
      for (int ee = 0; ee < 16; ++ee) {
        if (tbase + ee < E) {
          const int de = __builtin_amdgcn_readfirstlane(sDst[w][ee]);
          const float nv = xb[ee * 68 + l];
          if (de != run_d) {
            atomicAdd(&num[(size_t)run_d * 64 + l], acc);
            run_d = de; acc = 0.f;
          }
          acc += nv;
        }
      }
      atomicAdd(&num[(size_t)run_d * 64 + l], acc);
    }
#pragma unroll
    for (int t = 0; t < 4; ++t)
      *(f32x4*)&xb[lo * 68 + t * 16 + hi * 4] = exv[t];
    LGKM0;
    {
      int run_d = __builtin_amdgcn_readfirstlane(sDst[w][0]);
      float acc = 0.f;
#pragma unroll
      for (int ee = 0; ee < 16; ++ee) {
        if (tbase + ee < E) {
          const int de = __builtin_amdgcn_readfirstlane(sDst[w][ee]);
          const float dv = xb[ee * 68 + l];
          if (de != run_d) {
            atomicAdd(&den[(size_t)run_d * 64 + l], acc);
            run_d = de; acc = 0.f;
          }
          acc += dv;
        }
      }
      atomicAdd(&den[(size_t)run_d * 64 + l], acc);
    }
  }
#undef WF
}

// ================= node_out (MFMA) =================
__global__ __launch_bounds__(512, 4) void node_out_mfma(
    const float* __restrict__ num, const float* __restrict__ den,
    const uint4* __restrict__ frag, const float* __restrict__ b_out,
    float* __restrict__ out, int N) {
  __shared__ uint32_t sWfrag[8][64][4];
  __shared__ float    sBias[64];
  __shared__ float    sXp[8][16 * 68];

  const int tid = threadIdx.x;
  {
    uint4* sW4 = (uint4*)sWfrag;
    const uint4* srcf = frag + 56 * 64;
    for (int i = tid; i < 8 * 64; i += 512) sW4[i] = srcf[i];
  }
  if (tid < 64) sBias[tid] = b_out[tid];
  __syncthreads();

  const int w  = tid >> 6, l = tid & 63;
  const int lo = l & 15,  hi = l >> 4;
  float* xb = &sXp[w][0];

#define WFo(half, t) (*(const bf16x8*)&sWfrag[(half) * 4 + (t)][l][0])

  const int ntiles = (N + 15) >> 4;
  for (int tile = blockIdx.x * 8 + w; tile < ntiles; tile += gridDim.x * 8) {
    const int row = tile * 16 + lo;
    const int rowc = row < N ? row : (N - 1);
    bf16x8 sf[2];
#pragma unroll
    for (int half = 0; half < 2; ++half) {
      const int base = 32 * half + hi * 8;
      const f32x4 N0 = *(const f32x4*)&num[(size_t)rowc * 64 + base];
      const f32x4 N1 = *(const f32x4*)&num[(size_t)rowc * 64 + base + 4];
      const f32x4 D0 = *(const f32x4*)&den[(size_t)rowc * 64 + base];
      const f32x4 D1 = *(const f32x4*)&den[(size_t)rowc * 64 + base + 4];
      float t8[8];
#pragma unroll
      for (int i = 0; i < 8; ++i) {
        const float nn = (i < 4) ? N0[i] : N1[i - 4];
        const float dd = (i < 4) ? D0[i] : D1[i - 4];
        t8[i] = nn / (dd + 1e-16f);
      }
      sf[half] = mk8(cvtpk(t8[0], t8[1]), cvtpk(t8[2], t8[3]),
                     cvtpk(t8[4], t8[5]), cvtpk(t8[6], t8[7]));
    }
    f32x4 res[4];
#pragma unroll
    for (int t = 0; t < 4; ++t) {
      f32x4 acc = *(const f32x4*)&sBias[t * 16 + hi * 4];
      acc = mfma16(WFo(0, t), sf[0], acc);
      acc = mfma16(WFo(1, t), sf[1], acc);
#pragma unroll
      for (int r = 0; r < 4; ++r) res[t][r] = fmaxf(acc[r], 0.f);
    }
    LGKM0;
#pragma unroll
    for (int t = 0; t < 4; ++t)
      *(f32x4*)&xb[lo * 68 + t * 16 + hi * 4] = res[t];
    LGKM0;
#pragma unroll
    for (int ee = 0; ee < 16; ++ee) {
      const int r2 = tile * 16 + ee;
      if (r2 < N) out[(size_t)r2 * 64 + l] = xb[ee * 68 + l];
    }
  }
#undef WFo
}

extern "C" void kernel_launch(void* const* d_in, const int* in_sizes, int n_in,
                              void* d_out, int out_size, void* d_ws, size_t ws_size,
                              hipStream_t stream) {
  const float* x     = (const float*)d_in[0];
  const float* pos   = (const float*)d_in[1];
  const float* W_in  = (const float*)d_in[2];
  const float* b_in  = (const float*)d_in[3];
  const float* W_lin = (const float*)d_in[4];
  const float* W_src = (const float*)d_in[5];
  const float* W_dst = (const float*)d_in[6];
  const float* pW1   = (const float*)d_in[7];
  const float* pb1   = (const float*)d_in[8];
  const float* pW2   = (const float*)d_in[9];
  const float* pb2   = (const float*)d_in[10];
  const float* aW1   = (const float*)d_in[11];
  const float* ab1   = (const float*)d_in[12];
  const float* aW2   = (const float*)d_in[13];
  const float* ab2   = (const float*)d_in[14];
  const float* W_out = (const float*)d_in[15];
  const float* b_out = (const float*)d_in[16];
  const int*   eidx  = (const int*)d_in[17];

  const int N = in_sizes[0] / 64;
  const int E = in_sizes[17] / 2;

  // workspace layout: cursor first (only memset region)
  char* p = (char*)d_ws;
  int*   cursor = (int*)p;    p += (size_t)N * 4;
  const size_t memset_bytes = (size_t)p - (size_t)d_ws;
  int*   bsum   = (int*)p;    p += 64 * 4;
  p = (char*)(((uintptr_t)p + 15) & ~(uintptr_t)15);
  float* num    = (float*)p;  p += (size_t)N * 64 * 4;
  float* den    = (float*)p;  p += (size_t)N * 64 * 4;
  uint4* frag   = (uint4*)p;  p += (size_t)4096 * 16;
  uint32_t* sorted = (uint32_t*)p; p += (size_t)E * 4;
  unsigned short* vbf = (unsigned short*)p; p += (size_t)N * 64 * 2;
  unsigned short* abf = (unsigned short*)p; p += (size_t)N * 64 * 2;
  float* adst   = (float*)p;  p += (size_t)N * 64 * 4;

  hipMemsetAsync(cursor, 0, memset_bytes, stream);

  const int ZB = 104;                    // zero-role blocks (num+den)
  const int zquads = 2 * N * 16;         // 16B quads
  const int HB = (E + 1023) / 1024;      // hist blocks (4 edges/thread)
  const int NB_NODE = 784;
  fused_prep_kernel<<<16 + ZB + HB + NB_NODE, 256, 0, stream>>>(
      pW2, aW1, aW2, W_in, W_lin, W_src, W_dst, W_out, frag,
      (uint4*)num, zquads,
      eidx, cursor, E,
      x, b_in, vbf, abf, adst, N, ZB, HB);

  const int nb = (N + SCAN_CH - 1) / SCAN_CH;
  scan_blocksum<<<nb, 256, 0, stream>>>(cursor, bsum, N);
  scan_final<<<nb, 256, 0, stream>>>(cursor, bsum, N);
  scatter_kernel<<<(E + 255) / 256, 256, 0, stream>>>(eidx, cursor, sorted, E);

  edge_mfma_kernel<<<512, 512, 0, stream>>>(pos, vbf, abf, adst,
                                            pW1, pb1, pb2, ab1, ab2,
                                            frag, sorted, num, den, E);
  node_out_mfma<<<392, 512, 0, stream>>>(num, den, frag, b_out, (float*)d_out, N);
}

// Round 12
// 200.046 us; speedup vs baseline: 1.3122x; 1.0408x over previous
//
#include <hip/hip_runtime.h>
#include <hip/hip_bf16.h>

// Round 12: edge-kernel chain trims on the proven R8/R11 structure:
//  (1) pos-L1 weights as per-hi float4 broadcast records -> 16 ds_read_b128/tile
//      (was 64 ds_read_b32). (2) epilogue run-length via v_readlane on the dst
//      register (sDst LDS broadcast deleted; invalid lanes zeroed once).
//  (3) aW2/ab2 pre-scaled by log2(e) -> exp2f (saves 16 v_mul/tile).
// Aux chain identical to R11.

using bf16x8 = __attribute__((ext_vector_type(8))) short;
using f32x4  = __attribute__((ext_vector_type(4))) float;
using u16x8  = __attribute__((ext_vector_type(8))) unsigned short;
using u16x4  = __attribute__((ext_vector_type(4))) unsigned short;

#define LOG2E 1.4426950408889634f

__device__ __forceinline__ uint32_t cvtpk(float a, float b) {
  uint32_t d;
  asm("v_cvt_pk_bf16_f32 %0, %1, %2" : "=v"(d) : "v"(a), "v"(b));
  return d;
}
__device__ __forceinline__ float bf2f(unsigned short s) {
  union { uint32_t u; float f; } v; v.u = ((uint32_t)s) << 16;
  return v.f;
}
__device__ __forceinline__ float bf2fs(short s) { return bf2f((unsigned short)s); }
__device__ __forceinline__ bf16x8 mk8(uint32_t a, uint32_t b, uint32_t c, uint32_t d) {
  union { uint4 q; bf16x8 v; } u;
  u.q.x = a; u.q.y = b; u.q.z = c; u.q.w = d;
  return u.v;
}
__device__ __forceinline__ f32x4 mfma16(bf16x8 a, bf16x8 b, f32x4 c) {
  return __builtin_amdgcn_mfma_f32_16x16x32_bf16(a, b, c, 0, 0, 0);
}
#define LGKM0 asm volatile("s_waitcnt lgkmcnt(0)" ::: "memory")

// ================= fused prep: prepack + zero + hist + node_in =================
__global__ __launch_bounds__(256, 3) void fused_prep_kernel(
    const float* __restrict__ pW2, const float* __restrict__ aW1, const float* __restrict__ aW2,
    const float* __restrict__ W_in, const float* __restrict__ W_lin,
    const float* __restrict__ W_src, const float* __restrict__ W_dst,
    const float* __restrict__ W_out, uint4* __restrict__ frag,
    uint4* __restrict__ zbase, int zquads,
    const int* __restrict__ eidx, int* __restrict__ cursor, int E,
    const float* __restrict__ x, const float* __restrict__ b_in,
    unsigned short* __restrict__ vbf, unsigned short* __restrict__ abf,
    float* __restrict__ adst, int N, int ZB, int HB) {
  __shared__ uint32_t sWfrag[32][64][4];
  __shared__ float    sBias[64];
  __shared__ float    sXp[4][16 * 68];

  const int tid = threadIdx.x;

  // ---------- role: prepack (frag consumed ONLY by later dispatches) ----------
  if (blockIdx.x < 16) {
    const int idx = blockIdx.x * 256 + tid;
    const int f = idx >> 6, lane = idx & 63;
    const float* W; int fl;
    if      (f <  8) { W = pW2;   fl = f;      }
    else if (f < 16) { W = aW1;   fl = f -  8; }
    else if (f < 24) { W = aW2;   fl = f - 16; }
    else if (f < 32) { W = W_in;  fl = f - 24; }
    else if (f < 40) { W = W_lin; fl = f - 32; }
    else if (f < 48) { W = W_src; fl = f - 40; }
    else if (f < 56) { W = W_dst; fl = f - 48; }
    else             { W = W_out; fl = f - 56; }
    const float sc = (f >= 16 && f < 24) ? LOG2E : 1.0f;   // fold log2e into aW2
    const int half = (fl >> 2) & 1, t = fl & 3;
    const int lo = lane & 15, hi = lane >> 4;
    const int c = t * 16 + lo;
    const int k = 32 * half + hi * 8;
    uint4 q;
    q.x = cvtpk(W[(k + 0) * 64 + c] * sc, W[(k + 1) * 64 + c] * sc);
    q.y = cvtpk(W[(k + 2) * 64 + c] * sc, W[(k + 3) * 64 + c] * sc);
    q.z = cvtpk(W[(k + 4) * 64 + c] * sc, W[(k + 5) * 64 + c] * sc);
    q.w = cvtpk(W[(k + 6) * 64 + c] * sc, W[(k + 7) * 64 + c] * sc);
    frag[idx] = q;
    return;
  }
  int bid = blockIdx.x - 16;

  // ---------- role: zero num/den ----------
  if (bid < ZB) {
    const uint4 z = make_uint4(0, 0, 0, 0);
    for (int i = bid * 256 + tid; i < zquads; i += ZB * 256) zbase[i] = z;
    return;
  }
  bid -= ZB;

  // ---------- role: hist ----------
  if (bid < HB) {
    const int base = (bid * 256 + tid) * 4;
    if (base + 3 < E) {
      const int4 d = *(const int4*)(eidx + E + base);
      atomicAdd(&cursor[d.x], 1);
      atomicAdd(&cursor[d.y], 1);
      atomicAdd(&cursor[d.z], 1);
      atomicAdd(&cursor[d.w], 1);
    } else {
      for (int j = base; j < E; ++j) atomicAdd(&cursor[eidx[E + j]], 1);
    }
    return;
  }
  bid -= HB;
  const int nbn = gridDim.x - 16 - ZB - HB;

  // ---------- role: node_in ----------
  for (int idx = tid; idx < 32 * 64; idx += 256) {
    const int f = idx >> 6, lane = idx & 63;
    const int m = f >> 3, half = (f >> 2) & 1, t = f & 3;
    const float* W = (m == 0) ? W_in : (m == 1) ? W_lin : (m == 2) ? W_src : W_dst;
    const int lo = lane & 15, hi = lane >> 4;
    const int c = t * 16 + lo;
    const int k = 32 * half + hi * 8;
    uint4 q;
    q.x = cvtpk(W[(k + 0) * 64 + c], W[(k + 1) * 64 + c]);
    q.y = cvtpk(W[(k + 2) * 64 + c], W[(k + 3) * 64 + c]);
    q.z = cvtpk(W[(k + 4) * 64 + c], W[(k + 5) * 64 + c]);
    q.w = cvtpk(W[(k + 6) * 64 + c], W[(k + 7) * 64 + c]);
    *(uint4*)&sWfrag[f][lane][0] = q;
  }
  if (tid < 64) sBias[tid] = b_in[tid];
  __syncthreads();

  const int w  = tid >> 6, l = tid & 63;
  const int lo = l & 15,  hi = l >> 4;
  float*   xb     = &sXp[w][0];
  uint8_t* trbase = (uint8_t*)xb;
  const uint32_t swz = (uint32_t)((lo & 7) << 4);
  const int rr = l >> 5, cc = l & 31;

#define WF(m, half, t) (*(const bf16x8*)&sWfrag[(m) * 8 + (half) * 4 + (t)][l][0])

  const int ntiles = (N + 15) >> 4;
  for (int tile = bid * 4 + w; tile < ntiles; tile += nbn * 4) {
    const int row = tile * 16 + lo;
    const int rowc = row < N ? row : (N - 1);
    bf16x8 xf[2];
#pragma unroll
    for (int half = 0; half < 2; ++half) {
      const int base = 32 * half + hi * 8;
      const f32x4 X0 = *(const f32x4*)&x[(size_t)rowc * 64 + base];
      const f32x4 X1 = *(const f32x4*)&x[(size_t)rowc * 64 + base + 4];
      xf[half] = mk8(cvtpk(X0[0], X0[1]), cvtpk(X0[2], X0[3]),
                     cvtpk(X1[0], X1[1]), cvtpk(X1[2], X1[3]));
    }
    f32x4 x1[4];
#pragma unroll
    for (int t = 0; t < 4; ++t) {
      f32x4 acc = *(const f32x4*)&sBias[t * 16 + hi * 4];
      acc = mfma16(WF(0, 0, t), xf[0], acc);
      acc = mfma16(WF(0, 1, t), xf[1], acc);
#pragma unroll
      for (int r = 0; r < 4; ++r) x1[t][r] = fmaxf(acc[r], 0.f);
    }
    LGKM0;
#pragma unroll
    for (int t = 0; t < 4; ++t) {
      uint2 p; p.x = cvtpk(x1[t][0], x1[t][1]); p.y = cvtpk(x1[t][2], x1[t][3]);
      *(uint2*)(trbase + lo * 128 + (((uint32_t)(t * 32 + hi * 8)) ^ swz)) = p;
    }
    LGKM0;
    const bf16x8 x1f0 = *(const bf16x8*)(trbase + lo * 128 + (((uint32_t)(hi * 16)) ^ swz));
    const bf16x8 x1f1 = *(const bf16x8*)(trbase + lo * 128 + (((uint32_t)(64 + hi * 16)) ^ swz));

#pragma unroll
    for (int m = 1; m <= 3; ++m) {
      f32x4 res[4];
#pragma unroll
      for (int t = 0; t < 4; ++t) {
        f32x4 acc = {0.f, 0.f, 0.f, 0.f};
        acc = mfma16(WF(m, 0, t), x1f0, acc);
        acc = mfma16(WF(m, 1, t), x1f1, acc);
        res[t] = acc;
      }
#pragma unroll
      for (int t = 0; t < 4; ++t)
        *(f32x4*)&xb[lo * 68 + t * 16 + hi * 4] = res[t];
      LGKM0;
      if (m == 3) {
#pragma unroll
        for (int ee = 0; ee < 16; ++ee) {
          const int r2 = tile * 16 + ee;
          if (r2 < N) adst[(size_t)r2 * 64 + l] = xb[ee * 68 + l];
        }
      } else {
        unsigned short* outp = (m == 1) ? vbf : abf;
#pragma unroll
        for (int ee2 = 0; ee2 < 16; ee2 += 2) {
          const int er = ee2 + rr;
          const int r2 = tile * 16 + er;
          const uint32_t pk = cvtpk(xb[er * 68 + 2 * cc], xb[er * 68 + 2 * cc + 1]);
          if (r2 < N) *(uint32_t*)&outp[(size_t)r2 * 64 + 2 * cc] = pk;
        }
      }
      LGKM0;
    }
  }
#undef WF
}

// ================= scan (2 dispatches) =================
#define SCAN_CH 1024
__global__ __launch_bounds__(256) void scan_blocksum(
    const int* __restrict__ cursor, int* __restrict__ bsum, int N) {
  __shared__ int red[4];
  const int base = blockIdx.x * SCAN_CH + threadIdx.x * 4;
  int s = 0;
#pragma unroll
  for (int j = 0; j < 4; ++j) { const int i = base + j; if (i < N) s += cursor[i]; }
  for (int off = 1; off < 64; off <<= 1) s += __shfl_xor(s, off);
  if ((threadIdx.x & 63) == 0) red[threadIdx.x >> 6] = s;
  __syncthreads();
  if (threadIdx.x == 0) bsum[blockIdx.x] = red[0] + red[1] + red[2] + red[3];
}

__global__ __launch_bounds__(256) void scan_final(
    int* __restrict__ cursor, const int* __restrict__ bsum, int N) {
  __shared__ int woff[4];
  __shared__ int sBoff;
  const int tid = threadIdx.x;
  const int base = blockIdx.x * SCAN_CH + tid * 4;
  int xv[4]; int s = 0;
#pragma unroll
  for (int j = 0; j < 4; ++j) { const int i = base + j; xv[j] = (i < N) ? cursor[i] : 0; s += xv[j]; }
  int v = s;
  const int lane = tid & 63, wid = tid >> 6;
  for (int off = 1; off < 64; off <<= 1) {
    const int u = __shfl_up(v, off);
    if (lane >= off) v += u;
  }
  if (lane == 63) woff[wid] = v;
  if (tid < 64) {
    int val = (tid < (int)blockIdx.x) ? bsum[tid] : 0;
    for (int off = 1; off < 64; off <<= 1) val += __shfl_xor(val, off);
    if (tid == 0) sBoff = val;
  }
  __syncthreads();
  int waveoff = 0;
#pragma unroll
  for (int k = 0; k < 4; ++k) waveoff += (k < wid) ? woff[k] : 0;
  int ex = sBoff + waveoff + (v - s);
#pragma unroll
  for (int j = 0; j < 4; ++j) {
    const int i = base + j;
    if (i < N) { cursor[i] = ex; ex += xv[j]; }
  }
}

__global__ __launch_bounds__(256) void scatter_kernel(
    const int* __restrict__ eidx, int* __restrict__ cursor,
    uint32_t* __restrict__ sorted, int E) {
  const int e = blockIdx.x * 256 + threadIdx.x;
  if (e < E) {
    const int s = eidx[e];
    const int d = eidx[E + e];
    const int slot = atomicAdd(&cursor[d], 1);
    sorted[slot] = ((uint32_t)d << 16) | (uint32_t)s;
  }
}

// ================= edge kernel =================
__global__ __launch_bounds__(512, 4) void edge_mfma_kernel(
    const float* __restrict__ pos,
    const unsigned short* __restrict__ vbf, const unsigned short* __restrict__ abf,
    const float* __restrict__ adst,
    const float* __restrict__ pW1, const float* __restrict__ pb1,
    const float* __restrict__ pb2, const float* __restrict__ ab1, const float* __restrict__ ab2,
    const uint4* __restrict__ frag,
    const uint32_t* __restrict__ sorted,
    float* __restrict__ num, float* __restrict__ den, int E) {
  __shared__ uint32_t sWfrag[24][64][4];   // pW2, aW1, aW2(log2e-scaled)
  __shared__ float    sSmall[192];         // pb2 | ab1 | ab2*log2e
  __shared__ float    sPos[4 * 68];        // per-hi float4 records {pW1a,pW1b,pW1c,pb1}
  __shared__ float    sXp[8][16 * 68];

  const int tid = threadIdx.x;
  if (tid < 192) {
    float val;
    if      (tid < 64)  val = pb2[tid];
    else if (tid < 128) val = ab1[tid - 64];
    else                val = ab2[tid - 128] * LOG2E;
    sSmall[tid] = val;
  }
  if (tid < 256) {
    // sPos[hi*68 + j*4 + c], j = half*8+i, k = 32*half + 8*hi + i
    const int phi = tid >> 6, pj = (tid >> 2) & 15, pc = tid & 3;
    const int pk = 32 * (pj >> 3) + 8 * phi + (pj & 7);
    sPos[phi * 68 + pj * 4 + pc] = (pc < 3) ? pW1[pc * 64 + pk] : pb1[pk];
  }
  {
    uint4* sW4 = (uint4*)sWfrag;
    for (int i = tid; i < 24 * 64; i += 512) sW4[i] = frag[i];
  }
  __syncthreads();

  const int w  = tid >> 6, l = tid & 63;
  const int lo = l & 15,  hi = l >> 4;
  float*   xb     = &sXp[w][0];
  uint8_t* trbase = (uint8_t*)xb;
  const uint32_t swz = (uint32_t)((lo & 7) << 4);
  const int ho = hi * 8;

#define WF(m, half, t) (*(const bf16x8*)&sWfrag[(m) * 8 + (half) * 4 + (t)][l][0])

  const int ntiles = (E + 15) >> 4;
  const int stride = gridDim.x * 8;

  int cs = 0, cd = 0; float c0 = 0.f, c1 = 0.f, c2 = 0.f;
  {
    const int t0 = blockIdx.x * 8 + w;
    if (t0 < ntiles) {
      const int ee = t0 * 16 + lo;
      const int ec = ee < E ? ee : (E - 1);
      const uint32_t se = sorted[ec];
      cs = (int)(se & 0xFFFFu); cd = (int)(se >> 16);
      c0 = pos[cd * 3 + 0] - pos[cs * 3 + 0];
      c1 = pos[cd * 3 + 1] - pos[cs * 3 + 1];
      c2 = pos[cd * 3 + 2] - pos[cs * 3 + 2];
    }
  }

  for (int tile = blockIdx.x * 8 + w; tile < ntiles; tile += stride) {
    const int src = cs, dst = cd;
    const float d0 = c0, d1 = c1, d2 = c2;
    const bool valid = (tile * 16 + lo) < E;
    const size_t db = (size_t)dst * 64, sb = (size_t)src * 64;

    const f32x4 Ad00 = *(const f32x4*)&adst[db + ho];
    const f32x4 Ad01 = *(const f32x4*)&adst[db + ho + 4];
    const f32x4 Ad10 = *(const f32x4*)&adst[db + 32 + ho];
    const f32x4 Ad11 = *(const f32x4*)&adst[db + 32 + ho + 4];
    const u16x8 As0  = *(const u16x8*)&abf[sb + ho];
    const u16x8 As1  = *(const u16x8*)&abf[sb + 32 + ho];

    const int nt = tile + stride;
    if (nt < ntiles) {
      const int ee = nt * 16 + lo;
      const int ec = ee < E ? ee : (E - 1);
      const uint32_t se = sorted[ec];
      cs = (int)(se & 0xFFFFu); cd = (int)(se >> 16);
      c0 = pos[cd * 3 + 0] - pos[cs * 3 + 0];
      c1 = pos[cd * 3 + 1] - pos[cs * 3 + 1];
      c2 = pos[cd * 3 + 2] - pos[cs * 3 + 2];
    }

    // pos layer 1 (3->64): 16x ds_read_b128 broadcast, conflict-free
    bf16x8 hf[2];
#pragma unroll
    for (int half = 0; half < 2; ++half) {
      float t8[8];
#pragma unroll
      for (int i = 0; i < 8; ++i) {
        const f32x4 wv = *(const f32x4*)&sPos[hi * 68 + (half * 8 + i) * 4];
        t8[i] = fmaxf(wv[3] + d0 * wv[0] + d1 * wv[1] + d2 * wv[2], 0.f);
      }
      hf[half] = mk8(cvtpk(t8[0], t8[1]), cvtpk(t8[2], t8[3]),
                     cvtpk(t8[4], t8[5]), cvtpk(t8[6], t8[7]));
    }
    // pos layer 2
    f32x4 dl[4];
#pragma unroll
    for (int t = 0; t < 4; ++t) {
      f32x4 acc = *(const f32x4*)&sSmall[t * 16 + hi * 4];
      acc = mfma16(WF(0, 0, t), hf[0], acc);
      acc = mfma16(WF(0, 1, t), hf[1], acc);
#pragma unroll
      for (int r = 0; r < 4; ++r) dl[t][r] = fmaxf(acc[r], 0.f);
    }
    // transpose delta
    LGKM0;
#pragma unroll
    for (int t = 0; t < 4; ++t) {
      uint2 p; p.x = cvtpk(dl[t][0], dl[t][1]); p.y = cvtpk(dl[t][2], dl[t][3]);
      *(uint2*)(trbase + lo * 128 + (((uint32_t)(t * 32 + hi * 8)) ^ swz)) = p;
    }
    LGKM0;
    const bf16x8 dfr0 = *(const bf16x8*)(trbase + lo * 128 + (((uint32_t)(hi * 16)) ^ swz));
    const bf16x8 dfr1 = *(const bf16x8*)(trbase + lo * 128 + (((uint32_t)(64 + hi * 16)) ^ swz));

    bf16x8 tf[2];
    {
      float t8[8];
#pragma unroll
      for (int i = 0; i < 8; ++i)
        t8[i] = ((i < 4) ? Ad00[i] : Ad01[i - 4]) - bf2f(As0[i]) + bf2fs(dfr0[i]);
      tf[0] = mk8(cvtpk(t8[0], t8[1]), cvtpk(t8[2], t8[3]),
                  cvtpk(t8[4], t8[5]), cvtpk(t8[6], t8[7]));
#pragma unroll
      for (int i = 0; i < 8; ++i)
        t8[i] = ((i < 4) ? Ad10[i] : Ad11[i - 4]) - bf2f(As1[i]) + bf2fs(dfr1[i]);
      tf[1] = mk8(cvtpk(t8[0], t8[1]), cvtpk(t8[2], t8[3]),
                  cvtpk(t8[4], t8[5]), cvtpk(t8[6], t8[7]));
    }

    u16x4 V[4];
#pragma unroll
    for (int t = 0; t < 4; ++t) V[t] = *(const u16x4*)&vbf[sb + t * 16 + hi * 4];

    // attn layer 1
    f32x4 ga[4];
#pragma unroll
    for (int t = 0; t < 4; ++t) {
      f32x4 acc = *(const f32x4*)&sSmall[64 + t * 16 + hi * 4];
      acc = mfma16(WF(1, 0, t), tf[0], acc);
      acc = mfma16(WF(1, 1, t), tf[1], acc);
#pragma unroll
      for (int r = 0; r < 4; ++r) ga[t][r] = fmaxf(acc[r], 0.f);
    }
#pragma unroll
    for (int t = 0; t < 4; ++t) {
      uint2 p; p.x = cvtpk(ga[t][0], ga[t][1]); p.y = cvtpk(ga[t][2], ga[t][3]);
      *(uint2*)(trbase + 2048 + lo * 128 + (((uint32_t)(t * 32 + hi * 8)) ^ swz)) = p;
    }
    LGKM0;
    const bf16x8 gf0 = *(const bf16x8*)(trbase + 2048 + lo * 128 + (((uint32_t)(hi * 16)) ^ swz));
    const bf16x8 gf1 = *(const bf16x8*)(trbase + 2048 + lo * 128 + (((uint32_t)(64 + hi * 16)) ^ swz));

    // attn layer 2 -> exp2 (log2e folded into weights); zero invalid lanes
    f32x4 exv[4];
#pragma unroll
    for (int t = 0; t < 4; ++t) {
      f32x4 acc = *(const f32x4*)&sSmall[128 + t * 16 + hi * 4];
      acc = mfma16(WF(2, 0, t), gf0, acc);
      acc = mfma16(WF(2, 1, t), gf1, acc);
      f32x4 nv;
#pragma unroll
      for (int r = 0; r < 4; ++r) {
        float ex = exp2f(fmaxf(acc[r], 0.f));
        if (!valid) ex = 0.f;
        exv[t][r] = ex;
        nv[r] = ex * (bf2f(V[t][r]) + dl[t][r]);
      }
      *(f32x4*)&xb[lo * 68 + t * 16 + hi * 4] = nv;
    }
    LGKM0;
    // ---- pass 1: num (run-length, readlane-driven) ----
    {
      int run_d = __builtin_amdgcn_readlane(dst, 0);
      float acc = 0.f;
#pragma unroll
      for (int ee = 0; ee < 16; ++ee) {
        const int de = __builtin_amdgcn_readlane(dst, ee);
        const float nv = xb[ee * 68 + l];
        if (de != run_d) {
          atomicAdd(&num[(size_t)run_d * 64 + l], acc);
          run_d = de; acc = 0.f;
        }
        acc += nv;
      }
      atomicAdd(&num[(size_t)run_d * 64 + l], acc);
    }
#pragma unroll
    for (int t = 0; t < 4; ++t)
      *(f32x4*)&xb[lo * 68 + t * 16 + hi * 4] = exv[t];
    LGKM0;
    // ---- pass 2: den ----
    {
      int run_d = __builtin_amdgcn_readlane(dst, 0);
      float acc = 0.f;
#pragma unroll
      for (int ee = 0; ee < 16; ++ee) {
        const int de = __builtin_amdgcn_readlane(dst, ee);
        const float dv = xb[ee * 68 + l];
        if (de != run_d) {
          atomicAdd(&den[(size_t)run_d * 64 + l], acc);
          run_d = de; acc = 0.f;
        }
        acc += dv;
      }
      atomicAdd(&den[(size_t)run_d * 64 + l], acc);
    }
  }
#undef WF
}

// ================= node_out (MFMA) =================
__global__ __launch_bounds__(512, 4) void node_out_mfma(
    const float* __restrict__ num, const float* __restrict__ den,
    const uint4* __restrict__ frag, const float* __restrict__ b_out,
    float* __restrict__ out, int N) {
  __shared__ uint32_t sWfrag[8][64][4];
  __shared__ float    sBias[64];
  __shared__ float    sXp[8][16 * 68];

  const int tid = threadIdx.x;
  {
    uint4* sW4 = (uint4*)sWfrag;
    const uint4* srcf = frag + 56 * 64;
    for (int i = tid; i < 8 * 64; i += 512) sW4[i] = srcf[i];
  }
  if (tid < 64) sBias[tid] = b_out[tid];
  __syncthreads();

  const int w  = tid >> 6, l = tid & 63;
  const int lo = l & 15,  hi = l >> 4;
  float* xb = &sXp[w][0];

#define WFo(half, t) (*(const bf16x8*)&sWfrag[(half) * 4 + (t)][l][0])

  const int ntiles = (N + 15) >> 4;
  for (int tile = blockIdx.x * 8 + w; tile < ntiles; tile += gridDim.x * 8) {
    const int row = tile * 16 + lo;
    const int rowc = row < N ? row : (N - 1);
    bf16x8 sf[2];
#pragma unroll
    for (int half = 0; half < 2; ++half) {
      const int base = 32 * half + hi * 8;
      const f32x4 N0 = *(const f32x4*)&num[(size_t)rowc * 64 + base];
      const f32x4 N1 = *(const f32x4*)&num[(size_t)rowc * 64 + base + 4];
      const f32x4 D0 = *(const f32x4*)&den[(size_t)rowc * 64 + base];
      const f32x4 D1 = *(const f32x4*)&den[(size_t)rowc * 64 + base + 4];
      float t8[8];
#pragma unroll
      for (int i = 0; i < 8; ++i) {
        const float nn = (i < 4) ? N0[i] : N1[i - 4];
        const float dd = (i < 4) ? D0[i] : D1[i - 4];
        t8[i] = nn / (dd + 1e-16f);
      }
      sf[half] = mk8(cvtpk(t8[0], t8[1]), cvtpk(t8[2], t8[3]),
                     cvtpk(t8[4], t8[5]), cvtpk(t8[6], t8[7]));
    }
    f32x4 res[4];
#pragma unroll
    for (int t = 0; t < 4; ++t) {
      f32x4 acc = *(const f32x4*)&sBias[t * 16 + hi * 4];
      acc = mfma16(WFo(0, t), sf[0], acc);
      acc = mfma16(WFo(1, t), sf[1], acc);
#pragma unroll
      for (int r = 0; r < 4; ++r) res[t][r] = fmaxf(acc[r], 0.f);
    }
    LGKM0;
#pragma unroll
    for (int t = 0; t < 4; ++t)
      *(f32x4*)&xb[lo * 68 + t * 16 + hi * 4] = res[t];
    LGKM0;
#pragma unroll
    for (int ee = 0; ee < 16; ++ee) {
      const int r2 = tile * 16 + ee;
      if (r2 < N) out[(size_t)r2 * 64 + l] = xb[ee * 68 + l];
    }
  }
#undef WFo
}

extern "C" void kernel_launch(void* const* d_in, const int* in_sizes, int n_in,
                              void* d_out, int out_size, void* d_ws, size_t ws_size,
                              hipStream_t stream) {
  const float* x     = (const float*)d_in[0];
  const float* pos   = (const float*)d_in[1];
  const float* W_in  = (const float*)d_in[2];
  const float* b_in  = (const float*)d_in[3];
  const float* W_lin = (const float*)d_in[4];
  const float* W_src = (const float*)d_in[5];
  const float* W_dst = (const float*)d_in[6];
  const float* pW1   = (const float*)d_in[7];
  const float* pb1   = (const float*)d_in[8];
  const float* pW2   = (const float*)d_in[9];
  const float* pb2   = (const float*)d_in[10];
  const float* aW1   = (const float*)d_in[11];
  const float* ab1   = (const float*)d_in[12];
  const float* aW2   = (const float*)d_in[13];
  const float* ab2   = (const float*)d_in[14];
  const float* W_out = (const float*)d_in[15];
  const float* b_out = (const float*)d_in[16];
  const int*   eidx  = (const int*)d_in[17];

  const int N = in_sizes[0] / 64;
  const int E = in_sizes[17] / 2;

  char* p = (char*)d_ws;
  int*   cursor = (int*)p;    p += (size_t)N * 4;
  const size_t memset_bytes = (size_t)p - (size_t)d_ws;
  int*   bsum   = (int*)p;    p += 64 * 4;
  p = (char*)(((uintptr_t)p + 15) & ~(uintptr_t)15);
  float* num    = (float*)p;  p += (size_t)N * 64 * 4;
  float* den    = (float*)p;  p += (size_t)N * 64 * 4;
  uint4* frag   = (uint4*)p;  p += (size_t)4096 * 16;
  uint32_t* sorted = (uint32_t*)p; p += (size_t)E * 4;
  unsigned short* vbf = (unsigned short*)p; p += (size_t)N * 64 * 2;
  unsigned short* abf = (unsigned short*)p; p += (size_t)N * 64 * 2;
  float* adst   = (float*)p;  p += (size_t)N * 64 * 4;

  hipMemsetAsync(cursor, 0, memset_bytes, stream);

  const int ZB = 104;
  const int zquads = 2 * N * 16;
  const int HB = (E + 1023) / 1024;
  const int NB_NODE = 784;
  fused_prep_kernel<<<16 + ZB + HB + NB_NODE, 256, 0, stream>>>(
      pW2, aW1, aW2, W_in, W_lin, W_src, W_dst, W_out, frag,
      (uint4*)num, zquads,
      eidx, cursor, E,
      x, b_in, vbf, abf, adst, N, ZB, HB);

  const int nb = (N + SCAN_CH - 1) / SCAN_CH;
  scan_blocksum<<<nb, 256, 0, stream>>>(cursor, bsum, N);
  scan_final<<<nb, 256, 0, stream>>>(cursor, bsum, N);
  scatter_kernel<<<(E + 255) / 256, 256, 0, stream>>>(eidx, cursor, sorted, E);

  edge_mfma_kernel<<<512, 512, 0, stream>>>(pos, vbf, abf, adst,
                                            pW1, pb1, pb2, ab1, ab2,
                                            frag, sorted, num, den, E);
  node_out_mfma<<<392, 512, 0, stream>>>(num, den, frag, b_out, (float*)d_out, N);
}

// Round 14
// 198.546 us; speedup vs baseline: 1.3221x; 1.0076x over previous
//
#include <hip/hip_runtime.h>
#include <hip/hip_bf16.h>

// Round 14 = Round 13 with the LDS overflow fixed: ONE 2048B transpose region
// per wave (reused delta->ga; same-wave LDS ops are in-order so the ga write
// cannot pass the dfr read). Per-wave scratch 2176B; edge LDS ~43.8KB ->
// 3 blocks/CU (24 waves). bf16 epilogue staging + bf16 adst as in R13.

using bf16x8 = __attribute__((ext_vector_type(8))) short;
using f32x4  = __attribute__((ext_vector_type(4))) float;
using u16x8  = __attribute__((ext_vector_type(8))) unsigned short;
using u16x4  = __attribute__((ext_vector_type(4))) unsigned short;

#define LOG2E 1.4426950408889634f

__device__ __forceinline__ uint32_t cvtpk(float a, float b) {
  uint32_t d;
  asm("v_cvt_pk_bf16_f32 %0, %1, %2" : "=v"(d) : "v"(a), "v"(b));
  return d;
}
__device__ __forceinline__ float bf2f(unsigned short s) {
  union { uint32_t u; float f; } v; v.u = ((uint32_t)s) << 16;
  return v.f;
}
__device__ __forceinline__ float bf2fs(short s) { return bf2f((unsigned short)s); }
__device__ __forceinline__ bf16x8 mk8(uint32_t a, uint32_t b, uint32_t c, uint32_t d) {
  union { uint4 q; bf16x8 v; } u;
  u.q.x = a; u.q.y = b; u.q.z = c; u.q.w = d;
  return u.v;
}
__device__ __forceinline__ f32x4 mfma16(bf16x8 a, bf16x8 b, f32x4 c) {
  return __builtin_amdgcn_mfma_f32_16x16x32_bf16(a, b, c, 0, 0, 0);
}
#define LGKM0 asm volatile("s_waitcnt lgkmcnt(0)" ::: "memory")

// ================= fused prep: prepack + zero + hist + node_in =================
__global__ __launch_bounds__(256, 3) void fused_prep_kernel(
    const float* __restrict__ pW2, const float* __restrict__ aW1, const float* __restrict__ aW2,
    const float* __restrict__ W_in, const float* __restrict__ W_lin,
    const float* __restrict__ W_src, const float* __restrict__ W_dst,
    const float* __restrict__ W_out, uint4* __restrict__ frag,
    uint4* __restrict__ zbase, int zquads,
    const int* __restrict__ eidx, int* __restrict__ cursor, int E,
    const float* __restrict__ x, const float* __restrict__ b_in,
    unsigned short* __restrict__ vbf, unsigned short* __restrict__ abf,
    unsigned short* __restrict__ dbf, int N, int ZB, int HB) {
  __shared__ uint32_t sWfrag[32][64][4];
  __shared__ float    sBias[64];
  __shared__ float    sXp[4][16 * 68];

  const int tid = threadIdx.x;

  // ---------- role: prepack ----------
  if (blockIdx.x < 16) {
    const int idx = blockIdx.x * 256 + tid;
    const int f = idx >> 6, lane = idx & 63;
    const float* W; int fl;
    if      (f <  8) { W = pW2;   fl = f;      }
    else if (f < 16) { W = aW1;   fl = f -  8; }
    else if (f < 24) { W = aW2;   fl = f - 16; }
    else if (f < 32) { W = W_in;  fl = f - 24; }
    else if (f < 40) { W = W_lin; fl = f - 32; }
    else if (f < 48) { W = W_src; fl = f - 40; }
    else if (f < 56) { W = W_dst; fl = f - 48; }
    else             { W = W_out; fl = f - 56; }
    const float sc = (f >= 16 && f < 24) ? LOG2E : 1.0f;
    const int half = (fl >> 2) & 1, t = fl & 3;
    const int lo = lane & 15, hi = lane >> 4;
    const int c = t * 16 + lo;
    const int k = 32 * half + hi * 8;
    uint4 q;
    q.x = cvtpk(W[(k + 0) * 64 + c] * sc, W[(k + 1) * 64 + c] * sc);
    q.y = cvtpk(W[(k + 2) * 64 + c] * sc, W[(k + 3) * 64 + c] * sc);
    q.z = cvtpk(W[(k + 4) * 64 + c] * sc, W[(k + 5) * 64 + c] * sc);
    q.w = cvtpk(W[(k + 6) * 64 + c] * sc, W[(k + 7) * 64 + c] * sc);
    frag[idx] = q;
    return;
  }
  int bid = blockIdx.x - 16;

  // ---------- role: zero num/den ----------
  if (bid < ZB) {
    const uint4 z = make_uint4(0, 0, 0, 0);
    for (int i = bid * 256 + tid; i < zquads; i += ZB * 256) zbase[i] = z;
    return;
  }
  bid -= ZB;

  // ---------- role: hist ----------
  if (bid < HB) {
    const int base = (bid * 256 + tid) * 4;
    if (base + 3 < E) {
      const int4 d = *(const int4*)(eidx + E + base);
      atomicAdd(&cursor[d.x], 1);
      atomicAdd(&cursor[d.y], 1);
      atomicAdd(&cursor[d.z], 1);
      atomicAdd(&cursor[d.w], 1);
    } else {
      for (int j = base; j < E; ++j) atomicAdd(&cursor[eidx[E + j]], 1);
    }
    return;
  }
  bid -= HB;
  const int nbn = gridDim.x - 16 - ZB - HB;

  // ---------- role: node_in ----------
  for (int idx = tid; idx < 32 * 64; idx += 256) {
    const int f = idx >> 6, lane = idx & 63;
    const int m = f >> 3, half = (f >> 2) & 1, t = f & 3;
    const float* W = (m == 0) ? W_in : (m == 1) ? W_lin : (m == 2) ? W_src : W_dst;
    const int lo = lane & 15, hi = lane >> 4;
    const int c = t * 16 + lo;
    const int k = 32 * half + hi * 8;
    uint4 q;
    q.x = cvtpk(W[(k + 0) * 64 + c], W[(k + 1) * 64 + c]);
    q.y = cvtpk(W[(k + 2) * 64 + c], W[(k + 3) * 64 + c]);
    q.z = cvtpk(W[(k + 4) * 64 + c], W[(k + 5) * 64 + c]);
    q.w = cvtpk(W[(k + 6) * 64 + c], W[(k + 7) * 64 + c]);
    *(uint4*)&sWfrag[f][lane][0] = q;
  }
  if (tid < 64) sBias[tid] = b_in[tid];
  __syncthreads();

  const int w  = tid >> 6, l = tid & 63;
  const int lo = l & 15,  hi = l >> 4;
  float*   xb     = &sXp[w][0];
  uint8_t* trbase = (uint8_t*)xb;
  const uint32_t swz = (uint32_t)((lo & 7) << 4);
  const int rr = l >> 5, cc = l & 31;

#define WF(m, half, t) (*(const bf16x8*)&sWfrag[(m) * 8 + (half) * 4 + (t)][l][0])

  const int ntiles = (N + 15) >> 4;
  for (int tile = bid * 4 + w; tile < ntiles; tile += nbn * 4) {
    const int row = tile * 16 + lo;
    const int rowc = row < N ? row : (N - 1);
    bf16x8 xf[2];
#pragma unroll
    for (int half = 0; half < 2; ++half) {
      const int base = 32 * half + hi * 8;
      const f32x4 X0 = *(const f32x4*)&x[(size_t)rowc * 64 + base];
      const f32x4 X1 = *(const f32x4*)&x[(size_t)rowc * 64 + base + 4];
      xf[half] = mk8(cvtpk(X0[0], X0[1]), cvtpk(X0[2], X0[3]),
                     cvtpk(X1[0], X1[1]), cvtpk(X1[2], X1[3]));
    }
    f32x4 x1[4];
#pragma unroll
    for (int t = 0; t < 4; ++t) {
      f32x4 acc = *(const f32x4*)&sBias[t * 16 + hi * 4];
      acc = mfma16(WF(0, 0, t), xf[0], acc);
      acc = mfma16(WF(0, 1, t), xf[1], acc);
#pragma unroll
      for (int r = 0; r < 4; ++r) x1[t][r] = fmaxf(acc[r], 0.f);
    }
    LGKM0;
#pragma unroll
    for (int t = 0; t < 4; ++t) {
      uint2 p; p.x = cvtpk(x1[t][0], x1[t][1]); p.y = cvtpk(x1[t][2], x1[t][3]);
      *(uint2*)(trbase + lo * 128 + (((uint32_t)(t * 32 + hi * 8)) ^ swz)) = p;
    }
    LGKM0;
    const bf16x8 x1f0 = *(const bf16x8*)(trbase + lo * 128 + (((uint32_t)(hi * 16)) ^ swz));
    const bf16x8 x1f1 = *(const bf16x8*)(trbase + lo * 128 + (((uint32_t)(64 + hi * 16)) ^ swz));

#pragma unroll
    for (int m = 1; m <= 3; ++m) {
      f32x4 res[4];
#pragma unroll
      for (int t = 0; t < 4; ++t) {
        f32x4 acc = {0.f, 0.f, 0.f, 0.f};
        acc = mfma16(WF(m, 0, t), x1f0, acc);
        acc = mfma16(WF(m, 1, t), x1f1, acc);
        res[t] = acc;
      }
#pragma unroll
      for (int t = 0; t < 4; ++t)
        *(f32x4*)&xb[lo * 68 + t * 16 + hi * 4] = res[t];
      LGKM0;
      unsigned short* outp = (m == 1) ? vbf : (m == 2) ? abf : dbf;
#pragma unroll
      for (int ee2 = 0; ee2 < 16; ee2 += 2) {
        const int er = ee2 + rr;
        const int r2 = tile * 16 + er;
        const uint32_t pk = cvtpk(xb[er * 68 + 2 * cc], xb[er * 68 + 2 * cc + 1]);
        if (r2 < N) *(uint32_t*)&outp[(size_t)r2 * 64 + 2 * cc] = pk;
      }
      LGKM0;
    }
  }
#undef WF
}

// ================= scan (2 dispatches) =================
#define SCAN_CH 1024
__global__ __launch_bounds__(256) void scan_blocksum(
    const int* __restrict__ cursor, int* __restrict__ bsum, int N) {
  __shared__ int red[4];
  const int base = blockIdx.x * SCAN_CH + threadIdx.x * 4;
  int s = 0;
#pragma unroll
  for (int j = 0; j < 4; ++j) { const int i = base + j; if (i < N) s += cursor[i]; }
  for (int off = 1; off < 64; off <<= 1) s += __shfl_xor(s, off);
  if ((threadIdx.x & 63) == 0) red[threadIdx.x >> 6] = s;
  __syncthreads();
  if (threadIdx.x == 0) bsum[blockIdx.x] = red[0] + red[1] + red[2] + red[3];
}

__global__ __launch_bounds__(256) void scan_final(
    int* __restrict__ cursor, const int* __restrict__ bsum, int N) {
  __shared__ int woff[4];
  __shared__ int sBoff;
  const int tid = threadIdx.x;
  const int base = blockIdx.x * SCAN_CH + tid * 4;
  int xv[4]; int s = 0;
#pragma unroll
  for (int j = 0; j < 4; ++j) { const int i = base + j; xv[j] = (i < N) ? cursor[i] : 0; s += xv[j]; }
  int v = s;
  const int lane = tid & 63, wid = tid >> 6;
  for (int off = 1; off < 64; off <<= 1) {
    const int u = __shfl_up(v, off);
    if (lane >= off) v += u;
  }
  if (lane == 63) woff[wid] = v;
  if (tid < 64) {
    int val = (tid < (int)blockIdx.x) ? bsum[tid] : 0;
    for (int off = 1; off < 64; off <<= 1) val += __shfl_xor(val, off);
    if (tid == 0) sBoff = val;
  }
  __syncthreads();
  int waveoff = 0;
#pragma unroll
  for (int k = 0; k < 4; ++k) waveoff += (k < wid) ? woff[k] : 0;
  int ex = sBoff + waveoff + (v - s);
#pragma unroll
  for (int j = 0; j < 4; ++j) {
    const int i = base + j;
    if (i < N) { cursor[i] = ex; ex += xv[j]; }
  }
}

__global__ __launch_bounds__(256) void scatter_kernel(
    const int* __restrict__ eidx, int* __restrict__ cursor,
    uint32_t* __restrict__ sorted, int E) {
  const int e = blockIdx.x * 256 + threadIdx.x;
  if (e < E) {
    const int s = eidx[e];
    const int d = eidx[E + e];
    const int slot = atomicAdd(&cursor[d], 1);
    sorted[slot] = ((uint32_t)d << 16) | (uint32_t)s;
  }
}

// ================= edge kernel =================
__global__ __launch_bounds__(512, 6) void edge_mfma_kernel(
    const float* __restrict__ pos,
    const unsigned short* __restrict__ vbf, const unsigned short* __restrict__ abf,
    const unsigned short* __restrict__ dbf,
    const float* __restrict__ pW1, const float* __restrict__ pb1,
    const float* __restrict__ pb2, const float* __restrict__ ab1, const float* __restrict__ ab2,
    const uint4* __restrict__ frag,
    const uint32_t* __restrict__ sorted,
    float* __restrict__ num, float* __restrict__ den, int E) {
  __shared__ uint32_t sWfrag[24][64][4];        // 24KB
  __shared__ float    sSmall[192];              // pb2 | ab1 | ab2*log2e
  __shared__ float    sPos[4 * 68];             // per-hi float4 {pW1a,pW1b,pW1c,pb1}
  __shared__ unsigned short sXp16[8][16 * 68];  // 17.4KB: 2176B/wave scratch
                                                // (transpose region = [0,2048), REUSED)

  const int tid = threadIdx.x;
  if (tid < 192) {
    float val;
    if      (tid < 64)  val = pb2[tid];
    else if (tid < 128) val = ab1[tid - 64];
    else                val = ab2[tid - 128] * LOG2E;
    sSmall[tid] = val;
  }
  if (tid < 256) {
    const int phi = tid >> 6, pj = (tid >> 2) & 15, pc = tid & 3;
    const int pk = 32 * (pj >> 3) + 8 * phi + (pj & 7);
    sPos[phi * 68 + pj * 4 + pc] = (pc < 3) ? pW1[pc * 64 + pk] : pb1[pk];
  }
  {
    uint4* sW4 = (uint4*)sWfrag;
    for (int i = tid; i < 24 * 64; i += 512) sW4[i] = frag[i];
  }
  __syncthreads();

  const int w  = tid >> 6, l = tid & 63;
  const int lo = l & 15,  hi = l >> 4;
  unsigned short* xb16 = &sXp16[w][0];
  uint32_t* xb32 = (uint32_t*)xb16;
  uint8_t* trbase = (uint8_t*)xb16;   // single 2048B transpose region, reused
  const uint32_t swz = (uint32_t)((lo & 7) << 4);
  const int ho = hi * 8;

#define WF(m, half, t) (*(const bf16x8*)&sWfrag[(m) * 8 + (half) * 4 + (t)][l][0])

  const int ntiles = (E + 15) >> 4;
  const int stride = gridDim.x * 8;

  int cs = 0, cd = 0; float c0 = 0.f, c1 = 0.f, c2 = 0.f;
  {
    const int t0 = blockIdx.x * 8 + w;
    if (t0 < ntiles) {
      const int ee = t0 * 16 + lo;
      const int ec = ee < E ? ee : (E - 1);
      const uint32_t se = sorted[ec];
      cs = (int)(se & 0xFFFFu); cd = (int)(se >> 16);
      c0 = pos[cd * 3 + 0] - pos[cs * 3 + 0];
      c1 = pos[cd * 3 + 1] - pos[cs * 3 + 1];
      c2 = pos[cd * 3 + 2] - pos[cs * 3 + 2];
    }
  }

  for (int tile = blockIdx.x * 8 + w; tile < ntiles; tile += stride) {
    const int src = cs, dst = cd;
    const float d0 = c0, d1 = c1, d2 = c2;
    const bool valid = (tile * 16 + lo) < E;
    const size_t db = (size_t)dst * 64, sb = (size_t)src * 64;

    const u16x8 Ad0 = *(const u16x8*)&dbf[db + ho];
    const u16x8 Ad1 = *(const u16x8*)&dbf[db + 32 + ho];
    const u16x8 As0 = *(const u16x8*)&abf[sb + ho];
    const u16x8 As1 = *(const u16x8*)&abf[sb + 32 + ho];

    const int nt = tile + stride;
    if (nt < ntiles) {
      const int ee = nt * 16 + lo;
      const int ec = ee < E ? ee : (E - 1);
      const uint32_t se = sorted[ec];
      cs = (int)(se & 0xFFFFu); cd = (int)(se >> 16);
      c0 = pos[cd * 3 + 0] - pos[cs * 3 + 0];
      c1 = pos[cd * 3 + 1] - pos[cs * 3 + 1];
      c2 = pos[cd * 3 + 2] - pos[cs * 3 + 2];
    }

    // pos layer 1 (3->64): broadcast float4 records
    bf16x8 hf[2];
#pragma unroll
    for (int half = 0; half < 2; ++half) {
      float t8[8];
#pragma unroll
      for (int i = 0; i < 8; ++i) {
        const f32x4 wv = *(const f32x4*)&sPos[hi * 68 + (half * 8 + i) * 4];
        t8[i] = fmaxf(wv[3] + d0 * wv[0] + d1 * wv[1] + d2 * wv[2], 0.f);
      }
      hf[half] = mk8(cvtpk(t8[0], t8[1]), cvtpk(t8[2], t8[3]),
                     cvtpk(t8[4], t8[5]), cvtpk(t8[6], t8[7]));
    }
    // pos layer 2
    f32x4 dl[4];
#pragma unroll
    for (int t = 0; t < 4; ++t) {
      f32x4 acc = *(const f32x4*)&sSmall[t * 16 + hi * 4];
      acc = mfma16(WF(0, 0, t), hf[0], acc);
      acc = mfma16(WF(0, 1, t), hf[1], acc);
#pragma unroll
      for (int r = 0; r < 4; ++r) dl[t][r] = fmaxf(acc[r], 0.f);
    }
    // transpose delta (region [0,2048))
    LGKM0;   // prior epilogue reads of this region complete
#pragma unroll
    for (int t = 0; t < 4; ++t) {
      uint2 p; p.x = cvtpk(dl[t][0], dl[t][1]); p.y = cvtpk(dl[t][2], dl[t][3]);
      *(uint2*)(trbase + lo * 128 + (((uint32_t)(t * 32 + hi * 8)) ^ swz)) = p;
    }
    LGKM0;
    const bf16x8 dfr0 = *(const bf16x8*)(trbase + lo * 128 + (((uint32_t)(hi * 16)) ^ swz));
    const bf16x8 dfr1 = *(const bf16x8*)(trbase + lo * 128 + (((uint32_t)(64 + hi * 16)) ^ swz));

    bf16x8 tf[2];
    {
      float t8[8];
#pragma unroll
      for (int i = 0; i < 8; ++i)
        t8[i] = bf2f(Ad0[i]) - bf2f(As0[i]) + bf2fs(dfr0[i]);
      tf[0] = mk8(cvtpk(t8[0], t8[1]), cvtpk(t8[2], t8[3]),
                  cvtpk(t8[4], t8[5]), cvtpk(t8[6], t8[7]));
#pragma unroll
      for (int i = 0; i < 8; ++i)
        t8[i] = bf2f(Ad1[i]) - bf2f(As1[i]) + bf2fs(dfr1[i]);
      tf[1] = mk8(cvtpk(t8[0], t8[1]), cvtpk(t8[2], t8[3]),
                  cvtpk(t8[4], t8[5]), cvtpk(t8[6], t8[7]));
    }

    u16x4 V[4];
#pragma unroll
    for (int t = 0; t < 4; ++t) V[t] = *(const u16x4*)&vbf[sb + t * 16 + hi * 4];

    // attn layer 1
    f32x4 ga[4];
#pragma unroll
    for (int t = 0; t < 4; ++t) {
      f32x4 acc = *(const f32x4*)&sSmall[64 + t * 16 + hi * 4];
      acc = mfma16(WF(1, 0, t), tf[0], acc);
      acc = mfma16(WF(1, 1, t), tf[1], acc);
#pragma unroll
      for (int r = 0; r < 4; ++r) ga[t][r] = fmaxf(acc[r], 0.f);
    }
    // transpose ga -> SAME region [0,2048) (dfr already consumed; same-wave
    // LDS ops are in-order so these writes cannot pass the reads above)
#pragma unroll
    for (int t = 0; t < 4; ++t) {
      uint2 p; p.x = cvtpk(ga[t][0], ga[t][1]); p.y = cvtpk(ga[t][2], ga[t][3]);
      *(uint2*)(trbase + lo * 128 + (((uint32_t)(t * 32 + hi * 8)) ^ swz)) = p;
    }
    LGKM0;
    const bf16x8 gf0 = *(const bf16x8*)(trbase + lo * 128 + (((uint32_t)(hi * 16)) ^ swz));
    const bf16x8 gf1 = *(const bf16x8*)(trbase + lo * 128 + (((uint32_t)(64 + hi * 16)) ^ swz));

    // attn layer 2 -> exp2 (log2e folded)
    f32x4 exv[4];
#pragma unroll
    for (int t = 0; t < 4; ++t) {
      f32x4 acc = *(const f32x4*)&sSmall[128 + t * 16 + hi * 4];
      acc = mfma16(WF(2, 0, t), gf0, acc);
      acc = mfma16(WF(2, 1, t), gf1, acc);
      f32x4 nv;
#pragma unroll
      for (int r = 0; r < 4; ++r) {
        float ex = exp2f(fmaxf(acc[r], 0.f));
        if (!valid) ex = 0.f;
        exv[t][r] = ex;
        nv[r] = ex * (bf2f(V[t][r]) + dl[t][r]);
      }
      // stage nv bf16: u32 idx lo*34 + t*8 + hi*2 (writes issued after gf reads)
      uint2 pk; pk.x = cvtpk(nv[0], nv[1]); pk.y = cvtpk(nv[2], nv[3]);
      *(uint2*)&xb32[lo * 34 + t * 8 + hi * 2] = pk;
    }
    LGKM0;
    // ---- pass 1: num ----
    {
      int run_d = __builtin_amdgcn_readlane(dst, 0);
      float acc = 0.f;
#pragma unroll
      for (int ee = 0; ee < 16; ++ee) {
        const int de = __builtin_amdgcn_readlane(dst, ee);
        const float nv = bf2f(xb16[ee * 68 + l]);
        if (de != run_d) {
          atomicAdd(&num[(size_t)run_d * 64 + l], acc);
          run_d = de; acc = 0.f;
        }
        acc += nv;
      }
      atomicAdd(&num[(size_t)run_d * 64 + l], acc);
    }
#pragma unroll
    for (int t = 0; t < 4; ++t) {
      uint2 pk; pk.x = cvtpk(exv[t][0], exv[t][1]); pk.y = cvtpk(exv[t][2], exv[t][3]);
      *(uint2*)&xb32[lo * 34 + t * 8 + hi * 2] = pk;
    }
    LGKM0;
    // ---- pass 2: den ----
    {
      int run_d = __builtin_amdgcn_readlane(dst, 0);
      float acc = 0.f;
#pragma unroll
      for (int ee = 0; ee < 16; ++ee) {
        const int de = __builtin_amdgcn_readlane(dst, ee);
        const float dv = bf2f(xb16[ee * 68 + l]);
        if (de != run_d) {
          atomicAdd(&den[(size_t)run_d * 64 + l], acc);
          run_d = de; acc = 0.f;
        }
        acc += dv;
      }
      atomicAdd(&den[(size_t)run_d * 64 + l], acc);
    }
  }
#undef WF
}

// ================= node_out (MFMA) =================
__global__ __launch_bounds__(512, 4) void node_out_mfma(
    const float* __restrict__ num, const float* __restrict__ den,
    const uint4* __restrict__ frag, const float* __restrict__ b_out,
    float* __restrict__ out, int N) {
  __shared__ uint32_t sWfrag[8][64][4];
  __shared__ float    sBias[64];
  __shared__ float    sXp[8][16 * 68];

  const int tid = threadIdx.x;
  {
    uint4* sW4 = (uint4*)sWfrag;
    const uint4* srcf = frag + 56 * 64;
    for (int i = tid; i < 8 * 64; i += 512) sW4[i] = srcf[i];
  }
  if (tid < 64) sBias[tid] = b_out[tid];
  __syncthreads();

  const int w  = tid >> 6, l = tid & 63;
  const int lo = l & 15,  hi = l >> 4;
  float* xb = &sXp[w][0];

#define WFo(half, t) (*(const bf16x8*)&sWfrag[(half) * 4 + (t)][l][0])

  const int ntiles = (N + 15) >> 4;
  for (int tile = blockIdx.x * 8 + w; tile < ntiles; tile += gridDim.x * 8) {
    const int row = tile * 16 + lo;
    const int rowc = row < N ? row : (N - 1);
    bf16x8 sf[2];
#pragma unroll
    for (int half = 0; half < 2; ++half) {
      const int base = 32 * half + hi * 8;
      const f32x4 N0 = *(const f32x4*)&num[(size_t)rowc * 64 + base];
      const f32x4 N1 = *(const f32x4*)&num[(size_t)rowc * 64 + base + 4];
      const f32x4 D0 = *(const f32x4*)&den[(size_t)rowc * 64 + base];
      const f32x4 D1 = *(const f32x4*)&den[(size_t)rowc * 64 + base + 4];
      float t8[8];
#pragma unroll
      for (int i = 0; i < 8; ++i) {
        const float nn = (i < 4) ? N0[i] : N1[i - 4];
        const float dd = (i < 4) ? D0[i] : D1[i - 4];
        t8[i] = nn / (dd + 1e-16f);
      }
      sf[half] = mk8(cvtpk(t8[0], t8[1]), cvtpk(t8[2], t8[3]),
                     cvtpk(t8[4], t8[5]), cvtpk(t8[6], t8[7]));
    }
    f32x4 res[4];
#pragma unroll
    for (int t = 0; t < 4; ++t) {
      f32x4 acc = *(const f32x4*)&sBias[t * 16 + hi * 4];
      acc = mfma16(WFo(0, t), sf[0], acc);
      acc = mfma16(WFo(1, t), sf[1], acc);
#pragma unroll
      for (int r = 0; r < 4; ++r) res[t][r] = fmaxf(acc[r], 0.f);
    }
    LGKM0;
#pragma unroll
    for (int t = 0; t < 4; ++t)
      *(f32x4*)&xb[lo * 68 + t * 16 + hi * 4] = res[t];
    LGKM0;
#pragma unroll
    for (int ee = 0; ee < 16; ++ee) {
      const int r2 = tile * 16 + ee;
      if (r2 < N) out[(size_t)r2 * 64 + l] = xb[ee * 68 + l];
    }
  }
#undef WFo
}

extern "C" void kernel_launch(void* const* d_in, const int* in_sizes, int n_in,
                              void* d_out, int out_size, void* d_ws, size_t ws_size,
                              hipStream_t stream) {
  const float* x     = (const float*)d_in[0];
  const float* pos   = (const float*)d_in[1];
  const float* W_in  = (const float*)d_in[2];
  const float* b_in  = (const float*)d_in[3];
  const float* W_lin = (const float*)d_in[4];
  const float* W_src = (const float*)d_in[5];
  const float* W_dst = (const float*)d_in[6];
  const float* pW1   = (const float*)d_in[7];
  const float* pb1   = (const float*)d_in[8];
  const float* pW2   = (const float*)d_in[9];
  const float* pb2   = (const float*)d_in[10];
  const float* aW1   = (const float*)d_in[11];
  const float* ab1   = (const float*)d_in[12];
  const float* aW2   = (const float*)d_in[13];
  const float* ab2   = (const float*)d_in[14];
  const float* W_out = (const float*)d_in[15];
  const float* b_out = (const float*)d_in[16];
  const int*   eidx  = (const int*)d_in[17];

  const int N = in_sizes[0] / 64;
  const int E = in_sizes[17] / 2;

  char* p = (char*)d_ws;
  int*   cursor = (int*)p;    p += (size_t)N * 4;
  const size_t memset_bytes = (size_t)p - (size_t)d_ws;
  int*   bsum   = (int*)p;    p += 64 * 4;
  p = (char*)(((uintptr_t)p + 15) & ~(uintptr_t)15);
  float* num    = (float*)p;  p += (size_t)N * 64 * 4;
  float* den    = (float*)p;  p += (size_t)N * 64 * 4;
  uint4* frag   = (uint4*)p;  p += (size_t)4096 * 16;
  uint32_t* sorted = (uint32_t*)p; p += (size_t)E * 4;
  unsigned short* vbf = (unsigned short*)p; p += (size_t)N * 64 * 2;
  unsigned short* abf = (unsigned short*)p; p += (size_t)N * 64 * 2;
  unsigned short* dbf = (unsigned short*)p; p += (size_t)N * 64 * 2;

  hipMemsetAsync(cursor, 0, memset_bytes, stream);

  const int ZB = 104;
  const int zquads = 2 * N * 16;
  const int HB = (E + 1023) / 1024;
  const int NB_NODE = 784;
  fused_prep_kernel<<<16 + ZB + HB + NB_NODE, 256, 0, stream>>>(
      pW2, aW1, aW2, W_in, W_lin, W_src, W_dst, W_out, frag,
      (uint4*)num, zquads,
      eidx, cursor, E,
      x, b_in, vbf, abf, dbf, N, ZB, HB);

  const int nb = (N + SCAN_CH - 1) / SCAN_CH;
  scan_blocksum<<<nb, 256, 0, stream>>>(cursor, bsum, N);
  scan_final<<<nb, 256, 0, stream>>>(cursor, bsum, N);
  scatter_kernel<<<(E + 255) / 256, 256, 0, stream>>>(eidx, cursor, sorted, E);

  edge_mfma_kernel<<<768, 512, 0, stream>>>(pos, vbf, abf, dbf,
                                            pW1, pb1, pb2, ab1, ab2,
                                            frag, sorted, num, den, E);
  node_out_mfma<<<392, 512, 0, stream>>>(num, den, frag, b_out, (float*)d_out, N);
}